// Round 3
// baseline (1003.139 us; speedup 1.0000x reference)
//
#include <hip/hip_runtime.h>
#include <math.h>

#define B_   4
#define S_   256
#define SK_  512
#define D_   1024
#define NH_  16
#define NKV_ 4
#define HD_  64
#define DE_  4096
#define NE_  8

typedef __attribute__((ext_vector_type(8))) short bf16x8;
typedef __attribute__((ext_vector_type(4))) float f32x4;

struct __align__(8) s4 { short x, y, z, w; };

#define MFMA(a,b,c) __builtin_amdgcn_mfma_f32_16x16x32_bf16(a,b,c,0,0,0)

__device__ __forceinline__ unsigned short f2b(float f) {  // RNE
  union { float f; unsigned u; } v; v.f = f;
  unsigned r = v.u + 0x7FFF + ((v.u >> 16) & 1);
  return (unsigned short)(r >> 16);
}

__device__ __forceinline__ unsigned short f2bh(float f) {  // round-half-up (matches old weight path)
  return (unsigned short)((__float_as_uint(f) + 0x8000u) >> 16);
}

// ---------------- transpose-convert: fp32 W[K][N] -> bf16 Wt[N][K], one 64x64 tile/block ----
__device__ __forceinline__ void tconv_tile(float (*T)[65],
                                           const float* __restrict__ W,
                                           short* __restrict__ Wt,
                                           int N, int K, int n0, int k0) {
  int t = threadIdx.x;
  int kk = t >> 4, n4 = (t & 15) * 4;
#pragma unroll
  for (int it = 0; it < 4; ++it) {
    float4 v = *(const float4*)(W + (size_t)(k0 + kk + 16 * it) * N + n0 + n4);
    T[kk + 16 * it][n4 + 0] = v.x;
    T[kk + 16 * it][n4 + 1] = v.y;
    T[kk + 16 * it][n4 + 2] = v.z;
    T[kk + 16 * it][n4 + 3] = v.w;
  }
  __syncthreads();
  int n = t >> 2, kb = (t & 3) * 16;
  bf16x8 o0, o1;
#pragma unroll
  for (int j = 0; j < 8; ++j) o0[j] = (short)f2bh(T[kb + j][n]);
#pragma unroll
  for (int j = 0; j < 8; ++j) o1[j] = (short)f2bh(T[kb + 8 + j][n]);
  short* dst = Wt + (size_t)(n0 + n) * K + k0 + kb;
  *(bf16x8*)dst = o0;
  *(bf16x8*)(dst + 8) = o1;
}

struct P8 {
  const float* s[8];
  short* d[8];
  int n[8];
};

// all 8 attention weights (K = D_ = 1024 for each); z picks the matrix
__global__ __launch_bounds__(256) void tconv_attn(P8 p) {
  int z = blockIdx.z;
  int N = p.n[z];
  if ((int)blockIdx.x * 64 >= N) return;
  __shared__ float T[64][65];
  tconv_tile(T, p.s[z], p.d[z], N, D_, blockIdx.x * 64, blockIdx.y * 64);
}

// one expert's w1/w3 (z=0/1: [1024][4096] -> [4096][1024]) and w2 (z=2: [4096][1024] -> [1024][4096])
__global__ __launch_bounds__(256) void tconv_moe(const float* __restrict__ w1,
                                                 const float* __restrict__ w3,
                                                 const float* __restrict__ w2,
                                                 short* __restrict__ w1t,
                                                 short* __restrict__ w3t,
                                                 short* __restrict__ w2t,
                                                 const int* __restrict__ eact, int e) {
  if (!eact[e]) return;
  __shared__ float T[64][65];
  int z = blockIdx.z;
  if (z == 0) {
    tconv_tile(T, w1 + (size_t)e * D_ * DE_, w1t, DE_, D_, blockIdx.x * 64, blockIdx.y * 64);
  } else if (z == 1) {
    tconv_tile(T, w3 + (size_t)e * D_ * DE_, w3t, DE_, D_, blockIdx.x * 64, blockIdx.y * 64);
  } else {
    int lin = blockIdx.y * 64 + blockIdx.x;       // 0..1023
    int nt = lin & 15, kt = lin >> 4;             // N=1024 -> 16 n-tiles, K=4096 -> 64 k-tiles
    tconv_tile(T, w2 + (size_t)e * DE_ * D_, w2t, D_, DE_, nt * 64, kt * 64);
  }
}

// ---------------- layernorm: fp32 in, bf16 out ----------------
__global__ __launch_bounds__(256) void ln_kernel(const float* __restrict__ x,
                                                 const float* __restrict__ g,
                                                 const float* __restrict__ be,
                                                 short* __restrict__ y) {
  int row = blockIdx.x, tid = threadIdx.x;
  const float4 v = ((const float4*)(x + (size_t)row * D_))[tid];
  float s  = v.x + v.y + v.z + v.w;
  float s2 = v.x*v.x + v.y*v.y + v.z*v.z + v.w*v.w;
  __shared__ float r1[256], r2[256];
  r1[tid] = s; r2[tid] = s2; __syncthreads();
  for (int off = 128; off > 0; off >>= 1) {
    if (tid < off) { r1[tid] += r1[tid+off]; r2[tid] += r2[tid+off]; }
    __syncthreads();
  }
  float mean = r1[0] * (1.0f / D_);
  float var  = r2[0] * (1.0f / D_) - mean * mean;
  float inv  = rsqrtf(var + 1e-5f);
  int c = tid * 4;
  s4 o;
  o.x = (short)f2b((v.x - mean) * inv * g[c]   + be[c]);
  o.y = (short)f2b((v.y - mean) * inv * g[c+1] + be[c+1]);
  o.z = (short)f2b((v.z - mean) * inv * g[c+2] + be[c+2]);
  o.w = (short)f2b((v.w - mean) * inv * g[c+3] + be[c+3]);
  *(s4*)(y + (size_t)row * D_ + c) = o;
}

// ---------------- cast fp32 -> bf16 ----------------
__global__ void cast_f2b(const float* __restrict__ in, short* __restrict__ out, int n) {
  int i = (blockIdx.x * 256 + threadIdx.x) * 4;
  if (i < n) {
    float4 v = *(const float4*)(in + i);
    s4 o; o.x=(short)f2b(v.x); o.y=(short)f2b(v.y); o.z=(short)f2b(v.z); o.w=(short)f2b(v.w);
    *(s4*)(out + i) = o;
  }
}

// ---------------- projection: Cb = bf16((A@W + bias) * scale), Wt[n][k] bf16 ----------------
__global__ __launch_bounds__(256) void proj_mfma(const short* __restrict__ A,
                                                 const short* __restrict__ Wt,
                                                 const float* __restrict__ bias,
                                                 short* __restrict__ Cb,
                                                 float scale, int N, int K) {
  int bn = blockIdx.x * 64, bm = blockIdx.y * 64;
  int lane = threadIdx.x & 63, wv = threadIdx.x >> 6;
  int wm = (wv & 1) * 32, wn = (wv >> 1) * 32;
  int quad = lane >> 4, l16 = lane & 15;
  f32x4 z4 = {0.f,0.f,0.f,0.f};
  f32x4 acc[2][2] = {{z4,z4},{z4,z4}};
  const short* a0p = A + (size_t)(bm + wm + l16) * K;
  const short* a1p = a0p + (size_t)16 * K;
  const short* w0p = Wt + (size_t)(bn + wn + l16) * K;
  const short* w1p = w0p + (size_t)16 * K;
#pragma unroll 2
  for (int k0 = 0; k0 < K; k0 += 32) {
    int ka = k0 + quad * 8;
    bf16x8 a0 = *(const bf16x8*)(a0p + ka);
    bf16x8 a1 = *(const bf16x8*)(a1p + ka);
    bf16x8 b0 = *(const bf16x8*)(w0p + ka);
    bf16x8 b1 = *(const bf16x8*)(w1p + ka);
    acc[0][0] = MFMA(a0, b0, acc[0][0]);
    acc[0][1] = MFMA(a0, b1, acc[0][1]);
    acc[1][0] = MFMA(a1, b0, acc[1][0]);
    acc[1][1] = MFMA(a1, b1, acc[1][1]);
  }
#pragma unroll
  for (int i = 0; i < 2; ++i)
#pragma unroll
    for (int j = 0; j < 2; ++j) {
      int n = bn + wn + j*16 + l16;
      float bs = bias[n];
#pragma unroll
      for (int r = 0; r < 4; ++r) {
        int m = bm + wm + i*16 + quad*4 + r;
        Cb[(size_t)m * N + n] = (short)f2b((acc[i][j][r] + bs) * scale);
      }
    }
}

// ---------------- V projection with transposed output: vT[b][256 d][512 skv] ----------------
__global__ __launch_bounds__(256) void proj_v_mfma(const short* __restrict__ A,
                                                   const short* __restrict__ Wt,
                                                   const float* __restrict__ bias,
                                                   short* __restrict__ vT,
                                                   int SKV, int K) {
  int bn = blockIdx.x * 64, bm = blockIdx.y * 64;
  int lane = threadIdx.x & 63, wv = threadIdx.x >> 6;
  int wm = (wv & 1) * 32, wn = (wv >> 1) * 32;
  int quad = lane >> 4, l16 = lane & 15;
  f32x4 z4 = {0.f,0.f,0.f,0.f};
  f32x4 acc[2][2] = {{z4,z4},{z4,z4}};
  const short* a0p = A + (size_t)(bm + wm + l16) * K;
  const short* a1p = a0p + (size_t)16 * K;
  const short* w0p = Wt + (size_t)(bn + wn + l16) * K;
  const short* w1p = w0p + (size_t)16 * K;
#pragma unroll 2
  for (int k0 = 0; k0 < K; k0 += 32) {
    int ka = k0 + quad * 8;
    bf16x8 a0 = *(const bf16x8*)(a0p + ka);
    bf16x8 a1 = *(const bf16x8*)(a1p + ka);
    bf16x8 b0 = *(const bf16x8*)(w0p + ka);
    bf16x8 b1 = *(const bf16x8*)(w1p + ka);
    acc[0][0] = MFMA(a0, b0, acc[0][0]);
    acc[0][1] = MFMA(a0, b1, acc[0][1]);
    acc[1][0] = MFMA(a1, b0, acc[1][0]);
    acc[1][1] = MFMA(a1, b1, acc[1][1]);
  }
  __shared__ float T[64][65];
#pragma unroll
  for (int i = 0; i < 2; ++i)
#pragma unroll
    for (int j = 0; j < 2; ++j) {
      int nl = wn + j*16 + l16;
      float bs = bias[bn + nl];
#pragma unroll
      for (int r = 0; r < 4; ++r)
        T[nl][wm + i*16 + quad*4 + r] = acc[i][j][r] + bs;
    }
  __syncthreads();
  int t = threadIdx.x;
  int nl = t >> 2, m4 = (t & 3) * 16;
  int bb = bm / SKV, skv0 = bm % SKV;
  short* dst = vT + ((size_t)bb * 256 + bn + nl) * 512 + skv0 + m4;
  bf16x8 o0, o1;
#pragma unroll
  for (int ii = 0; ii < 8; ++ii) o0[ii] = (short)f2b(T[nl][m4 + ii]);
#pragma unroll
  for (int ii = 0; ii < 8; ++ii) o1[ii] = (short)f2b(T[nl][m4 + 8 + ii]);
  *(bf16x8*)dst = o0;
  *(bf16x8*)(dst + 8) = o1;
}

// ---------------- O projection: out fp32 = A@W + bias + residin ----------------
__global__ __launch_bounds__(256) void proj_o_mfma(const short* __restrict__ A,
                                                   const short* __restrict__ Wt,
                                                   const float* __restrict__ bias,
                                                   const float* __restrict__ rin,
                                                   float* __restrict__ C, int N, int K) {
  int bn = blockIdx.x * 64, bm = blockIdx.y * 64;
  int lane = threadIdx.x & 63, wv = threadIdx.x >> 6;
  int wm = (wv & 1) * 32, wn = (wv >> 1) * 32;
  int quad = lane >> 4, l16 = lane & 15;
  f32x4 z4 = {0.f,0.f,0.f,0.f};
  f32x4 acc[2][2] = {{z4,z4},{z4,z4}};
  const short* a0p = A + (size_t)(bm + wm + l16) * K;
  const short* a1p = a0p + (size_t)16 * K;
  const short* w0p = Wt + (size_t)(bn + wn + l16) * K;
  const short* w1p = w0p + (size_t)16 * K;
#pragma unroll 2
  for (int k0 = 0; k0 < K; k0 += 32) {
    int ka = k0 + quad * 8;
    bf16x8 a0 = *(const bf16x8*)(a0p + ka);
    bf16x8 a1 = *(const bf16x8*)(a1p + ka);
    bf16x8 b0 = *(const bf16x8*)(w0p + ka);
    bf16x8 b1 = *(const bf16x8*)(w1p + ka);
    acc[0][0] = MFMA(a0, b0, acc[0][0]);
    acc[0][1] = MFMA(a0, b1, acc[0][1]);
    acc[1][0] = MFMA(a1, b0, acc[1][0]);
    acc[1][1] = MFMA(a1, b1, acc[1][1]);
  }
#pragma unroll
  for (int i = 0; i < 2; ++i)
#pragma unroll
    for (int j = 0; j < 2; ++j) {
      int n = bn + wn + j*16 + l16;
      float bs = bias[n];
#pragma unroll
      for (int r = 0; r < 4; ++r) {
        int m = bm + wm + i*16 + quad*4 + r;
        C[(size_t)m * N + n] = acc[i][j][r] + bs + rin[(size_t)m * N + n];
      }
    }
}

// ---------------- QK^T + mask -> fp32 scores ----------------
__global__ __launch_bounds__(256) void qk_mfma(const short* __restrict__ Q,
                                               const short* __restrict__ Kb,
                                               const float* __restrict__ mask,
                                               float* __restrict__ sc,
                                               int b0, int SKV) {
  int z = blockIdx.z, zb = z >> 4, h = z & 15, b = b0 + zb, kvh = h >> 2;
  int bk = blockIdx.x * 64, bq = blockIdx.y * 64;
  int lane = threadIdx.x & 63, wv = threadIdx.x >> 6;
  int wm = (wv & 1) * 32, wn = (wv >> 1) * 32;
  int quad = lane >> 4, l16 = lane & 15;
  f32x4 z4 = {0.f,0.f,0.f,0.f};
  f32x4 acc[2][2] = {{z4,z4},{z4,z4}};
  const short* q0 = Q + (size_t)(b*S_ + bq + wm + l16) * D_ + h * HD_;
  const short* q1 = q0 + (size_t)16 * D_;
  const short* k0p = Kb + (size_t)(b*SKV + bk + wn + l16) * (NKV_*HD_) + kvh * HD_;
  const short* k1p = k0p + (size_t)16 * (NKV_*HD_);
#pragma unroll
  for (int d0 = 0; d0 < HD_; d0 += 32) {
    int ka = d0 + quad * 8;
    bf16x8 a0 = *(const bf16x8*)(q0 + ka);
    bf16x8 a1 = *(const bf16x8*)(q1 + ka);
    bf16x8 b0f = *(const bf16x8*)(k0p + ka);
    bf16x8 b1f = *(const bf16x8*)(k1p + ka);
    acc[0][0] = MFMA(a0, b0f, acc[0][0]);
    acc[0][1] = MFMA(a0, b1f, acc[0][1]);
    acc[1][0] = MFMA(a1, b0f, acc[1][0]);
    acc[1][1] = MFMA(a1, b1f, acc[1][1]);
  }
#pragma unroll
  for (int i = 0; i < 2; ++i)
#pragma unroll
    for (int j = 0; j < 2; ++j) {
      int n = bk + wn + j*16 + l16;
#pragma unroll
      for (int r = 0; r < 4; ++r) {
        int m = bq + wm + i*16 + quad*4 + r;
        sc[((size_t)(zb*NH_ + h) * S_ + m) * SKV + n] =
            acc[i][j][r] + mask[((size_t)(b*S_ + m)) * SKV + n];
      }
    }
}

// ---------------- row softmax: fp32 scores in, bf16 P out (in place) ----------------
__global__ __launch_bounds__(256) void softmax_kernel(float* __restrict__ sc, int SKV, int nrows) {
  int row = blockIdx.x * 4 + (threadIdx.x >> 6);
  int lane = threadIdx.x & 63;
  if (row >= nrows) return;
  float* rp = sc + (size_t)row * SKV;
  short* sp = (short*)rp;
  float4 v[2];
  int nc = SKV >> 8;
  float mx = -1e30f;
#pragma unroll
  for (int c = 0; c < 2; ++c)
    if (c < nc) {
      v[c] = *(float4*)(rp + c*256 + lane*4);
      mx = fmaxf(mx, fmaxf(fmaxf(v[c].x, v[c].y), fmaxf(v[c].z, v[c].w)));
    }
#pragma unroll
  for (int m = 32; m > 0; m >>= 1) mx = fmaxf(mx, __shfl_xor(mx, m, 64));
  float ls = 0.f;
#pragma unroll
  for (int c = 0; c < 2; ++c)
    if (c < nc) {
      v[c].x = __expf(v[c].x - mx); v[c].y = __expf(v[c].y - mx);
      v[c].z = __expf(v[c].z - mx); v[c].w = __expf(v[c].w - mx);
      ls += v[c].x + v[c].y + v[c].z + v[c].w;
    }
#pragma unroll
  for (int m = 32; m > 0; m >>= 1) ls += __shfl_xor(ls, m, 64);
  float inv = 1.0f / ls;
#pragma unroll
  for (int c = 0; c < 2; ++c)
    if (c < nc) {
      s4 o;
      o.x = (short)f2b(v[c].x * inv); o.y = (short)f2b(v[c].y * inv);
      o.z = (short)f2b(v[c].z * inv); o.w = (short)f2b(v[c].w * inv);
      *(s4*)(sp + c*256 + lane*4) = o;
    }
}

// ---------------- P @ V -> attn out bf16 [b*S+q][h*64+d] ----------------
__global__ __launch_bounds__(256) void pv_mfma(const short* __restrict__ Pb,
                                               const short* __restrict__ vT,
                                               short* __restrict__ ob,
                                               int b0, int SKV) {
  int z = blockIdx.y, zb = z >> 4, h = z & 15, b = b0 + zb, kvh = h >> 2;
  int bq = blockIdx.x * 64;
  int lane = threadIdx.x & 63, wv = threadIdx.x >> 6;
  int wm = (wv & 1) * 32, wn = (wv >> 1) * 32;
  int quad = lane >> 4, l16 = lane & 15;
  f32x4 z4 = {0.f,0.f,0.f,0.f};
  f32x4 acc[2][2] = {{z4,z4},{z4,z4}};
  const short* p0 = Pb + ((size_t)(zb*NH_ + h) * S_ + bq + wm + l16) * (size_t)(2*SKV);
  const short* p1 = p0 + (size_t)16 * 2 * SKV;
  const short* v0 = vT + ((size_t)b * 256 + kvh*64 + wn + l16) * 512;
  const short* v1 = v0 + (size_t)16 * 512;
#pragma unroll 4
  for (int k0 = 0; k0 < SKV; k0 += 32) {
    int ka = k0 + quad * 8;
    bf16x8 a0 = *(const bf16x8*)(p0 + ka);
    bf16x8 a1 = *(const bf16x8*)(p1 + ka);
    bf16x8 b0f = *(const bf16x8*)(v0 + ka);
    bf16x8 b1f = *(const bf16x8*)(v1 + ka);
    acc[0][0] = MFMA(a0, b0f, acc[0][0]);
    acc[0][1] = MFMA(a0, b1f, acc[0][1]);
    acc[1][0] = MFMA(a1, b0f, acc[1][0]);
    acc[1][1] = MFMA(a1, b1f, acc[1][1]);
  }
#pragma unroll
  for (int i = 0; i < 2; ++i)
#pragma unroll
    for (int j = 0; j < 2; ++j) {
      int n = wn + j*16 + l16;
#pragma unroll
      for (int r = 0; r < 4; ++r) {
        int m = bq + wm + i*16 + quad*4 + r;
        ob[(size_t)(b*S_ + m) * D_ + h*HD_ + n] = (short)f2b(acc[i][j][r]);
      }
    }
}

// ---------------- MoE gate (one expert): H = bf16(gelu(x@W1e) * (x@W3e)) ----------------
__global__ __launch_bounds__(256) void moe_gate_mfma(const short* __restrict__ xlnb,
                                                     const short* __restrict__ w1t,
                                                     const short* __restrict__ w3t,
                                                     short* __restrict__ Hs,
                                                     const float* __restrict__ coef, int e) {
  int bn = blockIdx.x * 64, bm = blockIdx.y * 64;
  int b = bm >> 8;
  if (coef[e * B_ + b] == 0.0f) return;
  int lane = threadIdx.x & 63, wv = threadIdx.x >> 6;
  int wm = (wv & 1) * 32, wn = (wv >> 1) * 32;
  int quad = lane >> 4, l16 = lane & 15;
  f32x4 z4 = {0.f,0.f,0.f,0.f};
  f32x4 acc1[2][2] = {{z4,z4},{z4,z4}};
  f32x4 acc3[2][2] = {{z4,z4},{z4,z4}};
  const short* a0p = xlnb + (size_t)(bm + wm + l16) * D_;
  const short* a1p = a0p + (size_t)16 * D_;
  const short* w1p0 = w1t + (size_t)(bn + wn + l16) * D_;
  const short* w1p1 = w1p0 + (size_t)16 * D_;
  const short* w3p0 = w3t + (size_t)(bn + wn + l16) * D_;
  const short* w3p1 = w3p0 + (size_t)16 * D_;
#pragma unroll 2
  for (int k0 = 0; k0 < D_; k0 += 32) {
    int ka = k0 + quad * 8;
    bf16x8 a0 = *(const bf16x8*)(a0p + ka);
    bf16x8 a1 = *(const bf16x8*)(a1p + ka);
    bf16x8 b10 = *(const bf16x8*)(w1p0 + ka);
    bf16x8 b11 = *(const bf16x8*)(w1p1 + ka);
    bf16x8 b30 = *(const bf16x8*)(w3p0 + ka);
    bf16x8 b31 = *(const bf16x8*)(w3p1 + ka);
    acc1[0][0] = MFMA(a0, b10, acc1[0][0]);
    acc1[0][1] = MFMA(a0, b11, acc1[0][1]);
    acc1[1][0] = MFMA(a1, b10, acc1[1][0]);
    acc1[1][1] = MFMA(a1, b11, acc1[1][1]);
    acc3[0][0] = MFMA(a0, b30, acc3[0][0]);
    acc3[0][1] = MFMA(a0, b31, acc3[0][1]);
    acc3[1][0] = MFMA(a1, b30, acc3[1][0]);
    acc3[1][1] = MFMA(a1, b31, acc3[1][1]);
  }
  short* Hp = Hs + ((size_t)(b * S_) + (bm & 255)) * DE_;
#pragma unroll
  for (int i = 0; i < 2; ++i)
#pragma unroll
    for (int j = 0; j < 2; ++j) {
      int n = bn + wn + j*16 + l16;
#pragma unroll
      for (int r = 0; r < 4; ++r) {
        int lm = wm + i*16 + quad*4 + r;
        float c1 = acc1[i][j][r], c3 = acc3[i][j][r];
        float g = 0.5f * c1 * (1.0f + erff(c1 * 0.70710678118654752f));
        Hp[(size_t)lm * DE_ + n] = (short)f2b(g * c3);
      }
    }
}

// ---------------- MoE down (one expert): resid += coef * (H @ W2e), 4-way K-split ----------------
__global__ __launch_bounds__(256) void moe_down_mfma(const short* __restrict__ Hs,
                                                     const short* __restrict__ w2t,
                                                     float* resid,
                                                     const float* __restrict__ coef, int e) {
  int kc = blockIdx.z;
  int bn = blockIdx.x * 64, bm = blockIdx.y * 64;
  int b = bm >> 8;
  float cf = coef[e * B_ + b];
  if (cf == 0.0f) return;
  int lane = threadIdx.x & 63, wv = threadIdx.x >> 6;
  int wm = (wv & 1) * 32, wn = (wv >> 1) * 32;
  int quad = lane >> 4, l16 = lane & 15;
  f32x4 z4 = {0.f,0.f,0.f,0.f};
  f32x4 acc[2][2] = {{z4,z4},{z4,z4}};
  const short* a0p = Hs + ((size_t)(b * S_) + (bm & 255) + wm + l16) * DE_ + kc * 1024;
  const short* a1p = a0p + (size_t)16 * DE_;
  const short* w0p = w2t + (size_t)(bn + wn + l16) * DE_ + kc * 1024;
  const short* w1p = w0p + (size_t)16 * DE_;
#pragma unroll 2
  for (int k0 = 0; k0 < 1024; k0 += 32) {
    int ka = k0 + quad * 8;
    bf16x8 a0 = *(const bf16x8*)(a0p + ka);
    bf16x8 a1 = *(const bf16x8*)(a1p + ka);
    bf16x8 b0 = *(const bf16x8*)(w0p + ka);
    bf16x8 b1 = *(const bf16x8*)(w1p + ka);
    acc[0][0] = MFMA(a0, b0, acc[0][0]);
    acc[0][1] = MFMA(a0, b1, acc[0][1]);
    acc[1][0] = MFMA(a1, b0, acc[1][0]);
    acc[1][1] = MFMA(a1, b1, acc[1][1]);
  }
#pragma unroll
  for (int i = 0; i < 2; ++i)
#pragma unroll
    for (int j = 0; j < 2; ++j) {
      int n = bn + wn + j*16 + l16;
#pragma unroll
      for (int r = 0; r < 4; ++r) {
        int m = bm + wm + i*16 + quad*4 + r;
        atomicAdd(&resid[(size_t)m * D_ + n], cf * acc[i][j][r]);
      }
    }
}

// ---------------- MoE routing coefficients + per-expert active flag ----------------
__global__ void coef_kernel(const int* __restrict__ langs, float* __restrict__ coef,
                            int* __restrict__ eact) {
  int t = threadIdx.x;
  if (t < NE_ * B_) {
    int e = t >> 2, b = t & 3;
    int l0 = langs[b*2], l1 = langs[b*2 + 1];
    int counts = (l0 > 3) + (l1 > 3);
    float rw = (counts == 0) ? 1.0f : 1.0f / (float)counts;
    bool m = (l0 == 4 + e) || (l1 == 4 + e);
    coef[t] = m ? rw : 0.0f;
  }
  if (t < NE_) {
    int any = 0;
    for (int b = 0; b < B_; ++b) {
      int l0 = langs[b*2], l1 = langs[b*2 + 1];
      any |= (l0 == 4 + t) || (l1 == 4 + t);
    }
    eact[t] = any;
  }
}

extern "C" void kernel_launch(void* const* d_in, const int* in_sizes, int n_in,
                              void* d_out, int out_size, void* d_ws, size_t ws_size,
                              hipStream_t stream) {
  const float* hidden = (const float*)d_in[0];
  const float* enc    = (const float*)d_in[1];
  const float* amask  = (const float*)d_in[2];
  const float* emask  = (const float*)d_in[3];
  const int*   langs  = (const int*)d_in[4];
  const float* ln1g = (const float*)d_in[5];
  const float* ln1b = (const float*)d_in[6];
  const float* saqw = (const float*)d_in[7];
  const float* saqb = (const float*)d_in[8];
  const float* sakw = (const float*)d_in[9];
  const float* sakb = (const float*)d_in[10];
  const float* savw = (const float*)d_in[11];
  const float* savb = (const float*)d_in[12];
  const float* saow = (const float*)d_in[13];
  const float* saob = (const float*)d_in[14];
  const float* ln2g = (const float*)d_in[15];
  const float* ln2b = (const float*)d_in[16];
  const float* caqw = (const float*)d_in[17];
  const float* caqb = (const float*)d_in[18];
  const float* cakw = (const float*)d_in[19];
  const float* cakb = (const float*)d_in[20];
  const float* cavw = (const float*)d_in[21];
  const float* cavb = (const float*)d_in[22];
  const float* caow = (const float*)d_in[23];
  const float* caob = (const float*)d_in[24];
  const float* ln3g = (const float*)d_in[25];
  const float* ln3b = (const float*)d_in[26];
  const float* w1   = (const float*)d_in[27];
  const float* w2   = (const float*)d_in[28];
  const float* w3   = (const float*)d_in[29];

  float* resid = (float*)d_out;     // fp32 residual stream lives in d_out

  const int M = B_ * S_;            // 1024
  float* ws = (float*)d_ws;
  short* xlnb = (short*)ws;  ws += (M * D_) / 2;          //  512K fl
  short* encb = (short*)ws;  ws += (B_ * SK_ * D_) / 2;   // 1024K fl
  short* qb   = (short*)ws;  ws += (M * D_) / 2;          //  512K fl
  short* kb   = (short*)ws;  ws += (B_ * SK_ * 256) / 2;  //  256K fl
  short* vT   = (short*)ws;  ws += (B_ * 256 * 512) / 2;  //  256K fl
  short* ab   = (short*)ws;  ws += (M * D_) / 2;          //  512K fl
  float* scb  = ws;          ws += B_ * NH_ * S_ * S_;    // 4194K fl (scores / P / MoE-H alias)
  float* coef = ws;          ws += 32;
  int*   eact = (int*)ws;    ws += 32;
  // bf16 transposed weights
  short* saqt = (short*)ws;  ws += (D_ * D_) / 2;         //  512K fl
  short* sakt = (short*)ws;  ws += (D_ * 256) / 2;        //  128K fl
  short* savt = (short*)ws;  ws += (D_ * 256) / 2;        //  128K fl
  short* saot = (short*)ws;  ws += (D_ * D_) / 2;         //  512K fl
  short* caqt = (short*)ws;  ws += (D_ * D_) / 2;
  short* cakt = (short*)ws;  ws += (D_ * 256) / 2;
  short* cavt = (short*)ws;  ws += (D_ * 256) / 2;
  short* caot = (short*)ws;  ws += (D_ * D_) / 2;
  short* w1t  = (short*)ws;  ws += (D_ * DE_) / 2;        // 2M fl (one expert)
  short* w3t  = (short*)ws;  ws += (D_ * DE_) / 2;        // 2M fl
  short* w2t  = (short*)ws;  ws += (D_ * DE_) / 2;        // 2M fl  — total ~64 MB
  short* Hs   = (short*)scb;                              // MoE hidden [B][S][DE] bf16 (one expert)

  dim3 blk(256);

  // ---- weight transpose-convert (attention) ----
  P8 p;
  p.s[0] = saqw; p.d[0] = saqt; p.n[0] = D_;
  p.s[1] = sakw; p.d[1] = sakt; p.n[1] = 256;
  p.s[2] = savw; p.d[2] = savt; p.n[2] = 256;
  p.s[3] = saow; p.d[3] = saot; p.n[3] = D_;
  p.s[4] = caqw; p.d[4] = caqt; p.n[4] = D_;
  p.s[5] = cakw; p.d[5] = cakt; p.n[5] = 256;
  p.s[6] = cavw; p.d[6] = cavt; p.n[6] = 256;
  p.s[7] = caow; p.d[7] = caot; p.n[7] = D_;
  tconv_attn<<<dim3(16, 16, 8), blk, 0, stream>>>(p);

  // ---- self attention ----
  ln_kernel<<<M, blk, 0, stream>>>(hidden, ln1g, ln1b, xlnb);
  proj_mfma<<<dim3(16, 16), blk, 0, stream>>>(xlnb, saqt, saqb, qb, 0.125f, D_, D_);
  proj_mfma<<<dim3(4, 16), blk, 0, stream>>>(xlnb, sakt, sakb, kb, 1.0f, 256, D_);
  proj_v_mfma<<<dim3(4, 16), blk, 0, stream>>>(xlnb, savt, savb, vT, 256, D_);
  qk_mfma<<<dim3(4, 4, 4*NH_), blk, 0, stream>>>(qb, kb, amask, scb, 0, S_);
  softmax_kernel<<<(4*NH_*S_)/4, blk, 0, stream>>>(scb, S_, 4*NH_*S_);
  pv_mfma<<<dim3(4, 4*NH_), blk, 0, stream>>>((short*)scb, vT, ab, 0, S_);
  proj_o_mfma<<<dim3(16, 16), blk, 0, stream>>>(ab, saot, saob, hidden, resid, D_, D_);

  // ---- cross attention ----
  ln_kernel<<<M, blk, 0, stream>>>(resid, ln2g, ln2b, xlnb);
  proj_mfma<<<dim3(16, 16), blk, 0, stream>>>(xlnb, caqt, caqb, qb, 0.125f, D_, D_);
  cast_f2b<<<(B_*SK_*D_)/1024, blk, 0, stream>>>(enc, encb, B_*SK_*D_);
  proj_mfma<<<dim3(4, 32), blk, 0, stream>>>(encb, cakt, cakb, kb, 1.0f, 256, D_);
  proj_v_mfma<<<dim3(4, 32), blk, 0, stream>>>(encb, cavt, cavb, vT, 512, D_);
  for (int b0 = 0; b0 < B_; b0 += 2) {   // 2 batches/pass: fp32 scores fit scb
    qk_mfma<<<dim3(8, 4, 2*NH_), blk, 0, stream>>>(qb, kb, emask, scb, b0, SK_);
    softmax_kernel<<<(2*NH_*S_)/4, blk, 0, stream>>>(scb, SK_, 2*NH_*S_);
    pv_mfma<<<dim3(4, 2*NH_), blk, 0, stream>>>((short*)scb, vT, ab, b0, SK_);
  }
  proj_o_mfma<<<dim3(16, 16), blk, 0, stream>>>(ab, caot, caob, resid, resid, D_, D_);

  // ---- MoE (experts sequential through one bf16 weight buffer) ----
  ln_kernel<<<M, blk, 0, stream>>>(resid, ln3g, ln3b, xlnb);
  coef_kernel<<<1, 64, 0, stream>>>(langs, coef, eact);
  for (int e = 0; e < NE_; ++e) {
    tconv_moe<<<dim3(64, 16, 3), blk, 0, stream>>>(w1, w3, w2, w1t, w3t, w2t, eact, e);
    moe_gate_mfma<<<dim3(DE_/64, M/64), blk, 0, stream>>>(xlnb, w1t, w3t, Hs, coef, e);
    moe_down_mfma<<<dim3(D_/64, M/64, 4), blk, 0, stream>>>(Hs, w2t, resid, coef, e);
  }
}

// Round 4
// 834.147 us; speedup vs baseline: 1.2026x; 1.2026x over previous
//
#include <hip/hip_runtime.h>
#include <math.h>

#define B_   4
#define S_   256
#define SK_  512
#define D_   1024
#define NH_  16
#define NKV_ 4
#define HD_  64
#define DE_  4096
#define NE_  8

typedef __attribute__((ext_vector_type(8))) short bf16x8;
typedef __attribute__((ext_vector_type(4))) float f32x4;

struct __align__(8) s4 { short x, y, z, w; };

#define MFMA(a,b,c) __builtin_amdgcn_mfma_f32_16x16x32_bf16(a,b,c,0,0,0)

__device__ __forceinline__ unsigned short f2b(float f) {  // RNE
  union { float f; unsigned u; } v; v.f = f;
  unsigned r = v.u + 0x7FFF + ((v.u >> 16) & 1);
  return (unsigned short)(r >> 16);
}

__device__ __forceinline__ unsigned short f2bh(float f) {  // round-half-up (matches old weight path)
  return (unsigned short)((__float_as_uint(f) + 0x8000u) >> 16);
}

// ---------------- transpose-convert: fp32 W[K][N] -> bf16 Wt[N][K], one 64x64 tile/block ----
__device__ __forceinline__ void tconv_tile(float (*T)[65],
                                           const float* __restrict__ W,
                                           short* __restrict__ Wt,
                                           int N, int K, int n0, int k0) {
  int t = threadIdx.x;
  int kk = t >> 4, n4 = (t & 15) * 4;
#pragma unroll
  for (int it = 0; it < 4; ++it) {
    float4 v = *(const float4*)(W + (size_t)(k0 + kk + 16 * it) * N + n0 + n4);
    T[kk + 16 * it][n4 + 0] = v.x;
    T[kk + 16 * it][n4 + 1] = v.y;
    T[kk + 16 * it][n4 + 2] = v.z;
    T[kk + 16 * it][n4 + 3] = v.w;
  }
  __syncthreads();
  int n = t >> 2, kb = (t & 3) * 16;
  bf16x8 o0, o1;
#pragma unroll
  for (int j = 0; j < 8; ++j) o0[j] = (short)f2bh(T[kb + j][n]);
#pragma unroll
  for (int j = 0; j < 8; ++j) o1[j] = (short)f2bh(T[kb + 8 + j][n]);
  short* dst = Wt + (size_t)(n0 + n) * K + k0 + kb;
  *(bf16x8*)dst = o0;
  *(bf16x8*)(dst + 8) = o1;
}

struct P8 {
  const float* s[8];
  short* d[8];
  int n[8];
};

// all 8 attention weights (K = D_ = 1024 for each); z picks the matrix
__global__ __launch_bounds__(256) void tconv_attn(P8 p) {
  int z = blockIdx.z;
  int N = p.n[z];
  if ((int)blockIdx.x * 64 >= N) return;
  __shared__ float T[64][65];
  tconv_tile(T, p.s[z], p.d[z], N, D_, blockIdx.x * 64, blockIdx.y * 64);
}

// ALL experts in one launch: z = e*3 + m; m=0:w1, m=1:w3 ([1024][4096] -> [4096][1024]),
// m=2: w2 ([4096][1024] -> [1024][4096]). Inactive experts exit.
__global__ __launch_bounds__(256) void tconv_moe(const float* __restrict__ w1,
                                                 const float* __restrict__ w3,
                                                 const float* __restrict__ w2,
                                                 short* __restrict__ w1t,
                                                 short* __restrict__ w3t,
                                                 short* __restrict__ w2t,
                                                 const int* __restrict__ eact) {
  int z = blockIdx.z;
  int e = z / 3, m = z - e * 3;
  if (!eact[e]) return;
  __shared__ float T[64][65];
  size_t off = (size_t)e * D_ * DE_;
  if (m == 0) {
    tconv_tile(T, w1 + off, w1t + off, DE_, D_, blockIdx.x * 64, blockIdx.y * 64);
  } else if (m == 1) {
    tconv_tile(T, w3 + off, w3t + off, DE_, D_, blockIdx.x * 64, blockIdx.y * 64);
  } else {
    int lin = blockIdx.y * 64 + blockIdx.x;       // 0..1023
    int nt = lin & 15, kt = lin >> 4;             // N=1024 -> 16 n-tiles, K=4096 -> 64 k-tiles
    tconv_tile(T, w2 + off, w2t + off, D_, DE_, nt * 64, kt * 64);
  }
}

// ---------------- layernorm: fp32 in, bf16 out ----------------
__global__ __launch_bounds__(256) void ln_kernel(const float* __restrict__ x,
                                                 const float* __restrict__ g,
                                                 const float* __restrict__ be,
                                                 short* __restrict__ y) {
  int row = blockIdx.x, tid = threadIdx.x;
  const float4 v = ((const float4*)(x + (size_t)row * D_))[tid];
  float s  = v.x + v.y + v.z + v.w;
  float s2 = v.x*v.x + v.y*v.y + v.z*v.z + v.w*v.w;
  __shared__ float r1[256], r2[256];
  r1[tid] = s; r2[tid] = s2; __syncthreads();
  for (int off = 128; off > 0; off >>= 1) {
    if (tid < off) { r1[tid] += r1[tid+off]; r2[tid] += r2[tid+off]; }
    __syncthreads();
  }
  float mean = r1[0] * (1.0f / D_);
  float var  = r2[0] * (1.0f / D_) - mean * mean;
  float inv  = rsqrtf(var + 1e-5f);
  int c = tid * 4;
  s4 o;
  o.x = (short)f2b((v.x - mean) * inv * g[c]   + be[c]);
  o.y = (short)f2b((v.y - mean) * inv * g[c+1] + be[c+1]);
  o.z = (short)f2b((v.z - mean) * inv * g[c+2] + be[c+2]);
  o.w = (short)f2b((v.w - mean) * inv * g[c+3] + be[c+3]);
  *(s4*)(y + (size_t)row * D_ + c) = o;
}

// ---------------- cast fp32 -> bf16 ----------------
__global__ void cast_f2b(const float* __restrict__ in, short* __restrict__ out, int n) {
  int i = (blockIdx.x * 256 + threadIdx.x) * 4;
  if (i < n) {
    float4 v = *(const float4*)(in + i);
    s4 o; o.x=(short)f2b(v.x); o.y=(short)f2b(v.y); o.z=(short)f2b(v.z); o.w=(short)f2b(v.w);
    *(s4*)(out + i) = o;
  }
}

// ---------------- projection: Cb = bf16((A@W + bias) * scale), Wt[n][k] bf16 ----------------
__global__ __launch_bounds__(256) void proj_mfma(const short* __restrict__ A,
                                                 const short* __restrict__ Wt,
                                                 const float* __restrict__ bias,
                                                 short* __restrict__ Cb,
                                                 float scale, int N, int K) {
  int bn = blockIdx.x * 64, bm = blockIdx.y * 64;
  int lane = threadIdx.x & 63, wv = threadIdx.x >> 6;
  int wm = (wv & 1) * 32, wn = (wv >> 1) * 32;
  int quad = lane >> 4, l16 = lane & 15;
  f32x4 z4 = {0.f,0.f,0.f,0.f};
  f32x4 acc[2][2] = {{z4,z4},{z4,z4}};
  const short* a0p = A + (size_t)(bm + wm + l16) * K;
  const short* a1p = a0p + (size_t)16 * K;
  const short* w0p = Wt + (size_t)(bn + wn + l16) * K;
  const short* w1p = w0p + (size_t)16 * K;
#pragma unroll 2
  for (int k0 = 0; k0 < K; k0 += 32) {
    int ka = k0 + quad * 8;
    bf16x8 a0 = *(const bf16x8*)(a0p + ka);
    bf16x8 a1 = *(const bf16x8*)(a1p + ka);
    bf16x8 b0 = *(const bf16x8*)(w0p + ka);
    bf16x8 b1 = *(const bf16x8*)(w1p + ka);
    acc[0][0] = MFMA(a0, b0, acc[0][0]);
    acc[0][1] = MFMA(a0, b1, acc[0][1]);
    acc[1][0] = MFMA(a1, b0, acc[1][0]);
    acc[1][1] = MFMA(a1, b1, acc[1][1]);
  }
#pragma unroll
  for (int i = 0; i < 2; ++i)
#pragma unroll
    for (int j = 0; j < 2; ++j) {
      int n = bn + wn + j*16 + l16;
      float bs = bias[n];
#pragma unroll
      for (int r = 0; r < 4; ++r) {
        int m = bm + wm + i*16 + quad*4 + r;
        Cb[(size_t)m * N + n] = (short)f2b((acc[i][j][r] + bs) * scale);
      }
    }
}

// ---------------- V projection with transposed output: vT[b][256 d][512 skv] ----------------
__global__ __launch_bounds__(256) void proj_v_mfma(const short* __restrict__ A,
                                                   const short* __restrict__ Wt,
                                                   const float* __restrict__ bias,
                                                   short* __restrict__ vT,
                                                   int SKV, int K) {
  int bn = blockIdx.x * 64, bm = blockIdx.y * 64;
  int lane = threadIdx.x & 63, wv = threadIdx.x >> 6;
  int wm = (wv & 1) * 32, wn = (wv >> 1) * 32;
  int quad = lane >> 4, l16 = lane & 15;
  f32x4 z4 = {0.f,0.f,0.f,0.f};
  f32x4 acc[2][2] = {{z4,z4},{z4,z4}};
  const short* a0p = A + (size_t)(bm + wm + l16) * K;
  const short* a1p = a0p + (size_t)16 * K;
  const short* w0p = Wt + (size_t)(bn + wn + l16) * K;
  const short* w1p = w0p + (size_t)16 * K;
#pragma unroll 2
  for (int k0 = 0; k0 < K; k0 += 32) {
    int ka = k0 + quad * 8;
    bf16x8 a0 = *(const bf16x8*)(a0p + ka);
    bf16x8 a1 = *(const bf16x8*)(a1p + ka);
    bf16x8 b0 = *(const bf16x8*)(w0p + ka);
    bf16x8 b1 = *(const bf16x8*)(w1p + ka);
    acc[0][0] = MFMA(a0, b0, acc[0][0]);
    acc[0][1] = MFMA(a0, b1, acc[0][1]);
    acc[1][0] = MFMA(a1, b0, acc[1][0]);
    acc[1][1] = MFMA(a1, b1, acc[1][1]);
  }
  __shared__ float T[64][65];
#pragma unroll
  for (int i = 0; i < 2; ++i)
#pragma unroll
    for (int j = 0; j < 2; ++j) {
      int nl = wn + j*16 + l16;
      float bs = bias[bn + nl];
#pragma unroll
      for (int r = 0; r < 4; ++r)
        T[nl][wm + i*16 + quad*4 + r] = acc[i][j][r] + bs;
    }
  __syncthreads();
  int t = threadIdx.x;
  int nl = t >> 2, m4 = (t & 3) * 16;
  int bb = bm / SKV, skv0 = bm % SKV;
  short* dst = vT + ((size_t)bb * 256 + bn + nl) * 512 + skv0 + m4;
  bf16x8 o0, o1;
#pragma unroll
  for (int ii = 0; ii < 8; ++ii) o0[ii] = (short)f2b(T[nl][m4 + ii]);
#pragma unroll
  for (int ii = 0; ii < 8; ++ii) o1[ii] = (short)f2b(T[nl][m4 + 8 + ii]);
  *(bf16x8*)dst = o0;
  *(bf16x8*)(dst + 8) = o1;
}

// ---------------- O projection: out fp32 = A@W + bias + residin ----------------
__global__ __launch_bounds__(256) void proj_o_mfma(const short* __restrict__ A,
                                                   const short* __restrict__ Wt,
                                                   const float* __restrict__ bias,
                                                   const float* __restrict__ rin,
                                                   float* __restrict__ C, int N, int K) {
  int bn = blockIdx.x * 64, bm = blockIdx.y * 64;
  int lane = threadIdx.x & 63, wv = threadIdx.x >> 6;
  int wm = (wv & 1) * 32, wn = (wv >> 1) * 32;
  int quad = lane >> 4, l16 = lane & 15;
  f32x4 z4 = {0.f,0.f,0.f,0.f};
  f32x4 acc[2][2] = {{z4,z4},{z4,z4}};
  const short* a0p = A + (size_t)(bm + wm + l16) * K;
  const short* a1p = a0p + (size_t)16 * K;
  const short* w0p = Wt + (size_t)(bn + wn + l16) * K;
  const short* w1p = w0p + (size_t)16 * K;
#pragma unroll 2
  for (int k0 = 0; k0 < K; k0 += 32) {
    int ka = k0 + quad * 8;
    bf16x8 a0 = *(const bf16x8*)(a0p + ka);
    bf16x8 a1 = *(const bf16x8*)(a1p + ka);
    bf16x8 b0 = *(const bf16x8*)(w0p + ka);
    bf16x8 b1 = *(const bf16x8*)(w1p + ka);
    acc[0][0] = MFMA(a0, b0, acc[0][0]);
    acc[0][1] = MFMA(a0, b1, acc[0][1]);
    acc[1][0] = MFMA(a1, b0, acc[1][0]);
    acc[1][1] = MFMA(a1, b1, acc[1][1]);
  }
#pragma unroll
  for (int i = 0; i < 2; ++i)
#pragma unroll
    for (int j = 0; j < 2; ++j) {
      int n = bn + wn + j*16 + l16;
      float bs = bias[n];
#pragma unroll
      for (int r = 0; r < 4; ++r) {
        int m = bm + wm + i*16 + quad*4 + r;
        C[(size_t)m * N + n] = acc[i][j][r] + bs + rin[(size_t)m * N + n];
      }
    }
}

// ---------------- QK^T + mask -> fp32 scores ----------------
__global__ __launch_bounds__(256) void qk_mfma(const short* __restrict__ Q,
                                               const short* __restrict__ Kb,
                                               const float* __restrict__ mask,
                                               float* __restrict__ sc,
                                               int b0, int SKV) {
  int z = blockIdx.z, zb = z >> 4, h = z & 15, b = b0 + zb, kvh = h >> 2;
  int bk = blockIdx.x * 64, bq = blockIdx.y * 64;
  int lane = threadIdx.x & 63, wv = threadIdx.x >> 6;
  int wm = (wv & 1) * 32, wn = (wv >> 1) * 32;
  int quad = lane >> 4, l16 = lane & 15;
  f32x4 z4 = {0.f,0.f,0.f,0.f};
  f32x4 acc[2][2] = {{z4,z4},{z4,z4}};
  const short* q0 = Q + (size_t)(b*S_ + bq + wm + l16) * D_ + h * HD_;
  const short* q1 = q0 + (size_t)16 * D_;
  const short* k0p = Kb + (size_t)(b*SKV + bk + wn + l16) * (NKV_*HD_) + kvh * HD_;
  const short* k1p = k0p + (size_t)16 * (NKV_*HD_);
#pragma unroll
  for (int d0 = 0; d0 < HD_; d0 += 32) {
    int ka = d0 + quad * 8;
    bf16x8 a0 = *(const bf16x8*)(q0 + ka);
    bf16x8 a1 = *(const bf16x8*)(q1 + ka);
    bf16x8 b0f = *(const bf16x8*)(k0p + ka);
    bf16x8 b1f = *(const bf16x8*)(k1p + ka);
    acc[0][0] = MFMA(a0, b0f, acc[0][0]);
    acc[0][1] = MFMA(a0, b1f, acc[0][1]);
    acc[1][0] = MFMA(a1, b0f, acc[1][0]);
    acc[1][1] = MFMA(a1, b1f, acc[1][1]);
  }
#pragma unroll
  for (int i = 0; i < 2; ++i)
#pragma unroll
    for (int j = 0; j < 2; ++j) {
      int n = bk + wn + j*16 + l16;
#pragma unroll
      for (int r = 0; r < 4; ++r) {
        int m = bq + wm + i*16 + quad*4 + r;
        sc[((size_t)(zb*NH_ + h) * S_ + m) * SKV + n] =
            acc[i][j][r] + mask[((size_t)(b*S_ + m)) * SKV + n];
      }
    }
}

// ---------------- row softmax: fp32 scores in, bf16 P out (in place) ----------------
__global__ __launch_bounds__(256) void softmax_kernel(float* __restrict__ sc, int SKV, int nrows) {
  int row = blockIdx.x * 4 + (threadIdx.x >> 6);
  int lane = threadIdx.x & 63;
  if (row >= nrows) return;
  float* rp = sc + (size_t)row * SKV;
  short* sp = (short*)rp;
  float4 v[2];
  int nc = SKV >> 8;
  float mx = -1e30f;
#pragma unroll
  for (int c = 0; c < 2; ++c)
    if (c < nc) {
      v[c] = *(float4*)(rp + c*256 + lane*4);
      mx = fmaxf(mx, fmaxf(fmaxf(v[c].x, v[c].y), fmaxf(v[c].z, v[c].w)));
    }
#pragma unroll
  for (int m = 32; m > 0; m >>= 1) mx = fmaxf(mx, __shfl_xor(mx, m, 64));
  float ls = 0.f;
#pragma unroll
  for (int c = 0; c < 2; ++c)
    if (c < nc) {
      v[c].x = __expf(v[c].x - mx); v[c].y = __expf(v[c].y - mx);
      v[c].z = __expf(v[c].z - mx); v[c].w = __expf(v[c].w - mx);
      ls += v[c].x + v[c].y + v[c].z + v[c].w;
    }
#pragma unroll
  for (int m = 32; m > 0; m >>= 1) ls += __shfl_xor(ls, m, 64);
  float inv = 1.0f / ls;
#pragma unroll
  for (int c = 0; c < 2; ++c)
    if (c < nc) {
      s4 o;
      o.x = (short)f2b(v[c].x * inv); o.y = (short)f2b(v[c].y * inv);
      o.z = (short)f2b(v[c].z * inv); o.w = (short)f2b(v[c].w * inv);
      *(s4*)(sp + c*256 + lane*4) = o;
    }
}

// ---------------- P @ V -> attn out bf16 [b*S+q][h*64+d] ----------------
__global__ __launch_bounds__(256) void pv_mfma(const short* __restrict__ Pb,
                                               const short* __restrict__ vT,
                                               short* __restrict__ ob,
                                               int b0, int SKV) {
  int z = blockIdx.y, zb = z >> 4, h = z & 15, b = b0 + zb, kvh = h >> 2;
  int bq = blockIdx.x * 64;
  int lane = threadIdx.x & 63, wv = threadIdx.x >> 6;
  int wm = (wv & 1) * 32, wn = (wv >> 1) * 32;
  int quad = lane >> 4, l16 = lane & 15;
  f32x4 z4 = {0.f,0.f,0.f,0.f};
  f32x4 acc[2][2] = {{z4,z4},{z4,z4}};
  const short* p0 = Pb + ((size_t)(zb*NH_ + h) * S_ + bq + wm + l16) * (size_t)(2*SKV);
  const short* p1 = p0 + (size_t)16 * 2 * SKV;
  const short* v0 = vT + ((size_t)b * 256 + kvh*64 + wn + l16) * 512;
  const short* v1 = v0 + (size_t)16 * 512;
#pragma unroll 4
  for (int k0 = 0; k0 < SKV; k0 += 32) {
    int ka = k0 + quad * 8;
    bf16x8 a0 = *(const bf16x8*)(p0 + ka);
    bf16x8 a1 = *(const bf16x8*)(p1 + ka);
    bf16x8 b0f = *(const bf16x8*)(v0 + ka);
    bf16x8 b1f = *(const bf16x8*)(v1 + ka);
    acc[0][0] = MFMA(a0, b0f, acc[0][0]);
    acc[0][1] = MFMA(a0, b1f, acc[0][1]);
    acc[1][0] = MFMA(a1, b0f, acc[1][0]);
    acc[1][1] = MFMA(a1, b1f, acc[1][1]);
  }
#pragma unroll
  for (int i = 0; i < 2; ++i)
#pragma unroll
    for (int j = 0; j < 2; ++j) {
      int n = wn + j*16 + l16;
#pragma unroll
      for (int r = 0; r < 4; ++r) {
        int m = bq + wm + i*16 + quad*4 + r;
        ob[(size_t)(b*S_ + m) * D_ + h*HD_ + n] = (short)f2b(acc[i][j][r]);
      }
    }
}

// ---------------- MoE gate (all experts, z=e): H = bf16(gelu(x@W1e) * (x@W3e)) ----------------
__global__ __launch_bounds__(256) void moe_gate_mfma(const short* __restrict__ xlnb,
                                                     const short* __restrict__ w1t,
                                                     const short* __restrict__ w3t,
                                                     short* __restrict__ Hs,
                                                     const float* __restrict__ coef,
                                                     const int* __restrict__ slot) {
  int e = blockIdx.z;
  int bn = blockIdx.x * 64, bm = blockIdx.y * 64;
  int b = bm >> 8;
  if (coef[e * B_ + b] == 0.0f) return;
  int sl = slot[e * B_ + b];
  int lane = threadIdx.x & 63, wv = threadIdx.x >> 6;
  int wm = (wv & 1) * 32, wn = (wv >> 1) * 32;
  int quad = lane >> 4, l16 = lane & 15;
  f32x4 z4 = {0.f,0.f,0.f,0.f};
  f32x4 acc1[2][2] = {{z4,z4},{z4,z4}};
  f32x4 acc3[2][2] = {{z4,z4},{z4,z4}};
  size_t eoff = (size_t)e * D_ * DE_;
  const short* a0p = xlnb + (size_t)(bm + wm + l16) * D_;
  const short* a1p = a0p + (size_t)16 * D_;
  const short* w1p0 = w1t + eoff + (size_t)(bn + wn + l16) * D_;
  const short* w1p1 = w1p0 + (size_t)16 * D_;
  const short* w3p0 = w3t + eoff + (size_t)(bn + wn + l16) * D_;
  const short* w3p1 = w3p0 + (size_t)16 * D_;
#pragma unroll 2
  for (int k0 = 0; k0 < D_; k0 += 32) {
    int ka = k0 + quad * 8;
    bf16x8 a0 = *(const bf16x8*)(a0p + ka);
    bf16x8 a1 = *(const bf16x8*)(a1p + ka);
    bf16x8 b10 = *(const bf16x8*)(w1p0 + ka);
    bf16x8 b11 = *(const bf16x8*)(w1p1 + ka);
    bf16x8 b30 = *(const bf16x8*)(w3p0 + ka);
    bf16x8 b31 = *(const bf16x8*)(w3p1 + ka);
    acc1[0][0] = MFMA(a0, b10, acc1[0][0]);
    acc1[0][1] = MFMA(a0, b11, acc1[0][1]);
    acc1[1][0] = MFMA(a1, b10, acc1[1][0]);
    acc1[1][1] = MFMA(a1, b11, acc1[1][1]);
    acc3[0][0] = MFMA(a0, b30, acc3[0][0]);
    acc3[0][1] = MFMA(a0, b31, acc3[0][1]);
    acc3[1][0] = MFMA(a1, b30, acc3[1][0]);
    acc3[1][1] = MFMA(a1, b31, acc3[1][1]);
  }
  short* Hp = Hs + ((size_t)(sl * B_ + b) * S_ + (bm & 255)) * DE_;
#pragma unroll
  for (int i = 0; i < 2; ++i)
#pragma unroll
    for (int j = 0; j < 2; ++j) {
      int n = bn + wn + j*16 + l16;
#pragma unroll
      for (int r = 0; r < 4; ++r) {
        int lm = wm + i*16 + quad*4 + r;
        float c1 = acc1[i][j][r], c3 = acc3[i][j][r];
        float g = 0.5f * c1 * (1.0f + erff(c1 * 0.70710678118654752f));
        Hp[(size_t)lm * DE_ + n] = (short)f2b(g * c3);
      }
    }
}

// ---------------- MoE down (all experts, z=e*4+kc): resid += coef * (H @ W2e) ----------------
__global__ __launch_bounds__(256) void moe_down_mfma(const short* __restrict__ Hs,
                                                     const short* __restrict__ w2t,
                                                     float* resid,
                                                     const float* __restrict__ coef,
                                                     const int* __restrict__ slot) {
  int zc = blockIdx.z;
  int e = zc >> 2, kc = zc & 3;
  int bn = blockIdx.x * 64, bm = blockIdx.y * 64;
  int b = bm >> 8;
  float cf = coef[e * B_ + b];
  if (cf == 0.0f) return;
  int sl = slot[e * B_ + b];
  int lane = threadIdx.x & 63, wv = threadIdx.x >> 6;
  int wm = (wv & 1) * 32, wn = (wv >> 1) * 32;
  int quad = lane >> 4, l16 = lane & 15;
  f32x4 z4 = {0.f,0.f,0.f,0.f};
  f32x4 acc[2][2] = {{z4,z4},{z4,z4}};
  const short* a0p = Hs + ((size_t)(sl * B_ + b) * S_ + (bm & 255) + wm + l16) * DE_ + kc * 1024;
  const short* a1p = a0p + (size_t)16 * DE_;
  const short* w0p = w2t + (size_t)e * DE_ * D_ + (size_t)(bn + wn + l16) * DE_ + kc * 1024;
  const short* w1p = w0p + (size_t)16 * DE_;
#pragma unroll 2
  for (int k0 = 0; k0 < 1024; k0 += 32) {
    int ka = k0 + quad * 8;
    bf16x8 a0 = *(const bf16x8*)(a0p + ka);
    bf16x8 a1 = *(const bf16x8*)(a1p + ka);
    bf16x8 b0 = *(const bf16x8*)(w0p + ka);
    bf16x8 b1 = *(const bf16x8*)(w1p + ka);
    acc[0][0] = MFMA(a0, b0, acc[0][0]);
    acc[0][1] = MFMA(a0, b1, acc[0][1]);
    acc[1][0] = MFMA(a1, b0, acc[1][0]);
    acc[1][1] = MFMA(a1, b1, acc[1][1]);
  }
#pragma unroll
  for (int i = 0; i < 2; ++i)
#pragma unroll
    for (int j = 0; j < 2; ++j) {
      int n = bn + wn + j*16 + l16;
#pragma unroll
      for (int r = 0; r < 4; ++r) {
        int m = bm + wm + i*16 + quad*4 + r;
        atomicAdd(&resid[(size_t)m * D_ + n], cf * acc[i][j][r]);
      }
    }
}

// ---------------- MoE routing coefficients + slots + per-expert active flags ----------------
__global__ void coef_kernel(const int* __restrict__ langs, float* __restrict__ coef,
                            int* __restrict__ slot, int* __restrict__ eact) {
  int t = threadIdx.x;
  if (t < NE_ * B_) {
    int e = t >> 2, b = t & 3;
    int l0 = langs[b*2], l1 = langs[b*2 + 1];
    int counts = (l0 > 3) + (l1 > 3);
    float rw = (counts == 0) ? 1.0f : 1.0f / (float)counts;
    bool m = (l0 == 4 + e) || (l1 == 4 + e);
    coef[t] = m ? rw : 0.0f;
    int s = 0;
    for (int ep = 0; ep < e; ++ep) s += ((l0 == 4 + ep) || (l1 == 4 + ep)) ? 1 : 0;
    slot[t] = s;
  }
  if (t < NE_) {
    int any = 0;
    for (int b = 0; b < B_; ++b) {
      int l0 = langs[b*2], l1 = langs[b*2 + 1];
      any |= (l0 == 4 + t) || (l1 == 4 + t);
    }
    eact[t] = any;
  }
}

extern "C" void kernel_launch(void* const* d_in, const int* in_sizes, int n_in,
                              void* d_out, int out_size, void* d_ws, size_t ws_size,
                              hipStream_t stream) {
  const float* hidden = (const float*)d_in[0];
  const float* enc    = (const float*)d_in[1];
  const float* amask  = (const float*)d_in[2];
  const float* emask  = (const float*)d_in[3];
  const int*   langs  = (const int*)d_in[4];
  const float* ln1g = (const float*)d_in[5];
  const float* ln1b = (const float*)d_in[6];
  const float* saqw = (const float*)d_in[7];
  const float* saqb = (const float*)d_in[8];
  const float* sakw = (const float*)d_in[9];
  const float* sakb = (const float*)d_in[10];
  const float* savw = (const float*)d_in[11];
  const float* savb = (const float*)d_in[12];
  const float* saow = (const float*)d_in[13];
  const float* saob = (const float*)d_in[14];
  const float* ln2g = (const float*)d_in[15];
  const float* ln2b = (const float*)d_in[16];
  const float* caqw = (const float*)d_in[17];
  const float* caqb = (const float*)d_in[18];
  const float* cakw = (const float*)d_in[19];
  const float* cakb = (const float*)d_in[20];
  const float* cavw = (const float*)d_in[21];
  const float* cavb = (const float*)d_in[22];
  const float* caow = (const float*)d_in[23];
  const float* caob = (const float*)d_in[24];
  const float* ln3g = (const float*)d_in[25];
  const float* ln3b = (const float*)d_in[26];
  const float* w1   = (const float*)d_in[27];
  const float* w2   = (const float*)d_in[28];
  const float* w3   = (const float*)d_in[29];

  float* resid = (float*)d_out;     // fp32 residual stream lives in d_out

  const int M = B_ * S_;            // 1024
  float* ws = (float*)d_ws;
  short* xlnb = (short*)ws;  ws += (M * D_) / 2;          //    2 MB
  short* encb = (short*)ws;  ws += (B_ * SK_ * D_) / 2;   //    4 MB
  short* qb   = (short*)ws;  ws += (M * D_) / 2;          //    2 MB
  short* kb   = (short*)ws;  ws += (B_ * SK_ * 256) / 2;  //    1 MB
  short* vT   = (short*)ws;  ws += (B_ * 256 * 512) / 2;  //    1 MB
  short* ab   = (short*)ws;  ws += (M * D_) / 2;          //    2 MB
  float* scb  = ws;          ws += B_ * NH_ * S_ * SK_;   // 33.5 MB (scores all 4 batches / MoE-H alias)
  float* coef = ws;          ws += 32;
  int*   slot = (int*)ws;    ws += 32;
  int*   eact = (int*)ws;    ws += 32;
  // bf16 transposed weights
  short* saqt = (short*)ws;  ws += (D_ * D_) / 2;
  short* sakt = (short*)ws;  ws += (D_ * 256) / 2;
  short* savt = (short*)ws;  ws += (D_ * 256) / 2;
  short* saot = (short*)ws;  ws += (D_ * D_) / 2;
  short* caqt = (short*)ws;  ws += (D_ * D_) / 2;
  short* cakt = (short*)ws;  ws += (D_ * 256) / 2;
  short* cavt = (short*)ws;  ws += (D_ * 256) / 2;
  short* caot = (short*)ws;  ws += (D_ * D_) / 2;        // attn weights total ~10 MB
  short* w1t  = (short*)ws;  ws += (size_t)NE_ * D_ * DE_ / 2;  // 64 MB (all experts)
  short* w3t  = (short*)ws;  ws += (size_t)NE_ * D_ * DE_ / 2;  // 64 MB
  short* w2t  = (short*)ws;  ws += (size_t)NE_ * D_ * DE_ / 2;  // 64 MB  — total ~250 MB (ws is 512 MB)
  short* Hs   = (short*)scb;                              // MoE hidden [2 slots][B][S][DE] bf16 = 16 MB

  dim3 blk(256);

  // ---- weight transpose-convert (attention) ----
  P8 p;
  p.s[0] = saqw; p.d[0] = saqt; p.n[0] = D_;
  p.s[1] = sakw; p.d[1] = sakt; p.n[1] = 256;
  p.s[2] = savw; p.d[2] = savt; p.n[2] = 256;
  p.s[3] = saow; p.d[3] = saot; p.n[3] = D_;
  p.s[4] = caqw; p.d[4] = caqt; p.n[4] = D_;
  p.s[5] = cakw; p.d[5] = cakt; p.n[5] = 256;
  p.s[6] = cavw; p.d[6] = cavt; p.n[6] = 256;
  p.s[7] = caow; p.d[7] = caot; p.n[7] = D_;
  tconv_attn<<<dim3(16, 16, 8), blk, 0, stream>>>(p);
  coef_kernel<<<1, 64, 0, stream>>>(langs, coef, slot, eact);
  // MoE weight transpose for all active experts (one launch, overlaps nothing but is parallel)
  tconv_moe<<<dim3(64, 16, NE_ * 3), blk, 0, stream>>>(w1, w3, w2, w1t, w3t, w2t, eact);

  // ---- self attention ----
  ln_kernel<<<M, blk, 0, stream>>>(hidden, ln1g, ln1b, xlnb);
  proj_mfma<<<dim3(16, 16), blk, 0, stream>>>(xlnb, saqt, saqb, qb, 0.125f, D_, D_);
  proj_mfma<<<dim3(4, 16), blk, 0, stream>>>(xlnb, sakt, sakb, kb, 1.0f, 256, D_);
  proj_v_mfma<<<dim3(4, 16), blk, 0, stream>>>(xlnb, savt, savb, vT, 256, D_);
  qk_mfma<<<dim3(4, 4, 4*NH_), blk, 0, stream>>>(qb, kb, amask, scb, 0, S_);
  softmax_kernel<<<(4*NH_*S_)/4, blk, 0, stream>>>(scb, S_, 4*NH_*S_);
  pv_mfma<<<dim3(4, 4*NH_), blk, 0, stream>>>((short*)scb, vT, ab, 0, S_);
  proj_o_mfma<<<dim3(16, 16), blk, 0, stream>>>(ab, saot, saob, hidden, resid, D_, D_);

  // ---- cross attention (all 4 batches in one pass; scb holds 4*16*256*512 fp32) ----
  ln_kernel<<<M, blk, 0, stream>>>(resid, ln2g, ln2b, xlnb);
  proj_mfma<<<dim3(16, 16), blk, 0, stream>>>(xlnb, caqt, caqb, qb, 0.125f, D_, D_);
  cast_f2b<<<(B_*SK_*D_)/1024, blk, 0, stream>>>(enc, encb, B_*SK_*D_);
  proj_mfma<<<dim3(4, 32), blk, 0, stream>>>(encb, cakt, cakb, kb, 1.0f, 256, D_);
  proj_v_mfma<<<dim3(4, 32), blk, 0, stream>>>(encb, cavt, cavb, vT, 512, D_);
  qk_mfma<<<dim3(8, 4, 4*NH_), blk, 0, stream>>>(qb, kb, emask, scb, 0, SK_);
  softmax_kernel<<<(4*NH_*S_)/4, blk, 0, stream>>>(scb, SK_, 4*NH_*S_);
  pv_mfma<<<dim3(4, 4*NH_), blk, 0, stream>>>((short*)scb, vT, ab, 0, SK_);
  proj_o_mfma<<<dim3(16, 16), blk, 0, stream>>>(ab, caot, caob, resid, resid, D_, D_);

  // ---- MoE (all experts parallel; Hs aliases scb, 2 slots) ----
  ln_kernel<<<M, blk, 0, stream>>>(resid, ln3g, ln3b, xlnb);
  moe_gate_mfma<<<dim3(DE_/64, M/64, NE_), blk, 0, stream>>>(xlnb, w1t, w3t, Hs, coef, slot);
  moe_down_mfma<<<dim3(D_/64, M/64, NE_*4), blk, 0, stream>>>(Hs, w2t, resid, coef, slot);
}

// Round 5
// 729.362 us; speedup vs baseline: 1.3754x; 1.1437x over previous
//
#include <hip/hip_runtime.h>
#include <math.h>

#define B_   4
#define S_   256
#define SK_  512
#define D_   1024
#define NH_  16
#define NKV_ 4
#define HD_  64
#define DE_  4096
#define NE_  8

typedef __attribute__((ext_vector_type(8))) short bf16x8;
typedef __attribute__((ext_vector_type(4))) float f32x4;

struct __align__(8) s4 { short x, y, z, w; };

#define MFMA(a,b,c) __builtin_amdgcn_mfma_f32_16x16x32_bf16(a,b,c,0,0,0)

__device__ __forceinline__ unsigned short f2b(float f) {  // RNE
  union { float f; unsigned u; } v; v.f = f;
  unsigned r = v.u + 0x7FFF + ((v.u >> 16) & 1);
  return (unsigned short)(r >> 16);
}

__device__ __forceinline__ unsigned short f2bh(float f) {  // round-half-up (matches old weight path)
  return (unsigned short)((__float_as_uint(f) + 0x8000u) >> 16);
}

// ---------------- transpose-convert: fp32 W[K][N] -> bf16 Wt[N][K], one 64x64 tile/block ----
__device__ __forceinline__ void tconv_tile(float (*T)[65],
                                           const float* __restrict__ W,
                                           short* __restrict__ Wt,
                                           int N, int K, int n0, int k0) {
  int t = threadIdx.x;
  int kk = t >> 4, n4 = (t & 15) * 4;
#pragma unroll
  for (int it = 0; it < 4; ++it) {
    float4 v = *(const float4*)(W + (size_t)(k0 + kk + 16 * it) * N + n0 + n4);
    T[kk + 16 * it][n4 + 0] = v.x;
    T[kk + 16 * it][n4 + 1] = v.y;
    T[kk + 16 * it][n4 + 2] = v.z;
    T[kk + 16 * it][n4 + 3] = v.w;
  }
  __syncthreads();
  int n = t >> 2, kb = (t & 3) * 16;
  bf16x8 o0, o1;
#pragma unroll
  for (int j = 0; j < 8; ++j) o0[j] = (short)f2bh(T[kb + j][n]);
#pragma unroll
  for (int j = 0; j < 8; ++j) o1[j] = (short)f2bh(T[kb + 8 + j][n]);
  short* dst = Wt + (size_t)(n0 + n) * K + k0 + kb;
  *(bf16x8*)dst = o0;
  *(bf16x8*)(dst + 8) = o1;
}

struct P8 {
  const float* s[8];
  short* d[8];
  int n[8];
};

// all 8 attention weights (K = D_ = 1024 for each); z picks the matrix
__global__ __launch_bounds__(256) void tconv_attn(P8 p) {
  int z = blockIdx.z;
  int N = p.n[z];
  if ((int)blockIdx.x * 64 >= N) return;
  __shared__ float T[64][65];
  tconv_tile(T, p.s[z], p.d[z], N, D_, blockIdx.x * 64, blockIdx.y * 64);
}

// ALL experts in one launch: z = e*3 + m; m=0:w1, m=1:w3 ([1024][4096] -> [4096][1024]),
// m=2: w2 ([4096][1024] -> [1024][4096]). Inactive experts exit.
__global__ __launch_bounds__(256) void tconv_moe(const float* __restrict__ w1,
                                                 const float* __restrict__ w3,
                                                 const float* __restrict__ w2,
                                                 short* __restrict__ w1t,
                                                 short* __restrict__ w3t,
                                                 short* __restrict__ w2t,
                                                 const int* __restrict__ eact) {
  int z = blockIdx.z;
  int e = z / 3, m = z - e * 3;
  if (!eact[e]) return;
  __shared__ float T[64][65];
  size_t off = (size_t)e * D_ * DE_;
  if (m == 0) {
    tconv_tile(T, w1 + off, w1t + off, DE_, D_, blockIdx.x * 64, blockIdx.y * 64);
  } else if (m == 1) {
    tconv_tile(T, w3 + off, w3t + off, DE_, D_, blockIdx.x * 64, blockIdx.y * 64);
  } else {
    int lin = blockIdx.y * 64 + blockIdx.x;       // 0..1023
    int nt = lin & 15, kt = lin >> 4;             // N=1024 -> 16 n-tiles, K=4096 -> 64 k-tiles
    tconv_tile(T, w2 + off, w2t + off, D_, DE_, nt * 64, kt * 64);
  }
}

// ---------------- layernorm: fp32 in, bf16 out ----------------
__global__ __launch_bounds__(256) void ln_kernel(const float* __restrict__ x,
                                                 const float* __restrict__ g,
                                                 const float* __restrict__ be,
                                                 short* __restrict__ y) {
  int row = blockIdx.x, tid = threadIdx.x;
  const float4 v = ((const float4*)(x + (size_t)row * D_))[tid];
  float s  = v.x + v.y + v.z + v.w;
  float s2 = v.x*v.x + v.y*v.y + v.z*v.z + v.w*v.w;
  __shared__ float r1[256], r2[256];
  r1[tid] = s; r2[tid] = s2; __syncthreads();
  for (int off = 128; off > 0; off >>= 1) {
    if (tid < off) { r1[tid] += r1[tid+off]; r2[tid] += r2[tid+off]; }
    __syncthreads();
  }
  float mean = r1[0] * (1.0f / D_);
  float var  = r2[0] * (1.0f / D_) - mean * mean;
  float inv  = rsqrtf(var + 1e-5f);
  int c = tid * 4;
  s4 o;
  o.x = (short)f2b((v.x - mean) * inv * g[c]   + be[c]);
  o.y = (short)f2b((v.y - mean) * inv * g[c+1] + be[c+1]);
  o.z = (short)f2b((v.z - mean) * inv * g[c+2] + be[c+2]);
  o.w = (short)f2b((v.w - mean) * inv * g[c+3] + be[c+3]);
  *(s4*)(y + (size_t)row * D_ + c) = o;
}

// ---------------- cast fp32 -> bf16 ----------------
__global__ void cast_f2b(const float* __restrict__ in, short* __restrict__ out, int n) {
  int i = (blockIdx.x * 256 + threadIdx.x) * 4;
  if (i < n) {
    float4 v = *(const float4*)(in + i);
    s4 o; o.x=(short)f2b(v.x); o.y=(short)f2b(v.y); o.z=(short)f2b(v.z); o.w=(short)f2b(v.w);
    *(s4*)(out + i) = o;
  }
}

// ---------------- projection: Cb = bf16((A@W + bias) * scale), Wt[n][k] bf16 ----------------
__global__ __launch_bounds__(256) void proj_mfma(const short* __restrict__ A,
                                                 const short* __restrict__ Wt,
                                                 const float* __restrict__ bias,
                                                 short* __restrict__ Cb,
                                                 float scale, int N, int K) {
  int bn = blockIdx.x * 64, bm = blockIdx.y * 64;
  int lane = threadIdx.x & 63, wv = threadIdx.x >> 6;
  int wm = (wv & 1) * 32, wn = (wv >> 1) * 32;
  int quad = lane >> 4, l16 = lane & 15;
  f32x4 z4 = {0.f,0.f,0.f,0.f};
  f32x4 acc[2][2] = {{z4,z4},{z4,z4}};
  const short* a0p = A + (size_t)(bm + wm + l16) * K;
  const short* a1p = a0p + (size_t)16 * K;
  const short* w0p = Wt + (size_t)(bn + wn + l16) * K;
  const short* w1p = w0p + (size_t)16 * K;
#pragma unroll 2
  for (int k0 = 0; k0 < K; k0 += 32) {
    int ka = k0 + quad * 8;
    bf16x8 a0 = *(const bf16x8*)(a0p + ka);
    bf16x8 a1 = *(const bf16x8*)(a1p + ka);
    bf16x8 b0 = *(const bf16x8*)(w0p + ka);
    bf16x8 b1 = *(const bf16x8*)(w1p + ka);
    acc[0][0] = MFMA(a0, b0, acc[0][0]);
    acc[0][1] = MFMA(a0, b1, acc[0][1]);
    acc[1][0] = MFMA(a1, b0, acc[1][0]);
    acc[1][1] = MFMA(a1, b1, acc[1][1]);
  }
#pragma unroll
  for (int i = 0; i < 2; ++i)
#pragma unroll
    for (int j = 0; j < 2; ++j) {
      int n = bn + wn + j*16 + l16;
      float bs = bias[n];
#pragma unroll
      for (int r = 0; r < 4; ++r) {
        int m = bm + wm + i*16 + quad*4 + r;
        Cb[(size_t)m * N + n] = (short)f2b((acc[i][j][r] + bs) * scale);
      }
    }
}

// ---------------- V projection with transposed output: vT[b][256 d][512 skv] ----------------
__global__ __launch_bounds__(256) void proj_v_mfma(const short* __restrict__ A,
                                                   const short* __restrict__ Wt,
                                                   const float* __restrict__ bias,
                                                   short* __restrict__ vT,
                                                   int SKV, int K) {
  int bn = blockIdx.x * 64, bm = blockIdx.y * 64;
  int lane = threadIdx.x & 63, wv = threadIdx.x >> 6;
  int wm = (wv & 1) * 32, wn = (wv >> 1) * 32;
  int quad = lane >> 4, l16 = lane & 15;
  f32x4 z4 = {0.f,0.f,0.f,0.f};
  f32x4 acc[2][2] = {{z4,z4},{z4,z4}};
  const short* a0p = A + (size_t)(bm + wm + l16) * K;
  const short* a1p = a0p + (size_t)16 * K;
  const short* w0p = Wt + (size_t)(bn + wn + l16) * K;
  const short* w1p = w0p + (size_t)16 * K;
#pragma unroll 2
  for (int k0 = 0; k0 < K; k0 += 32) {
    int ka = k0 + quad * 8;
    bf16x8 a0 = *(const bf16x8*)(a0p + ka);
    bf16x8 a1 = *(const bf16x8*)(a1p + ka);
    bf16x8 b0 = *(const bf16x8*)(w0p + ka);
    bf16x8 b1 = *(const bf16x8*)(w1p + ka);
    acc[0][0] = MFMA(a0, b0, acc[0][0]);
    acc[0][1] = MFMA(a0, b1, acc[0][1]);
    acc[1][0] = MFMA(a1, b0, acc[1][0]);
    acc[1][1] = MFMA(a1, b1, acc[1][1]);
  }
  __shared__ float T[64][65];
#pragma unroll
  for (int i = 0; i < 2; ++i)
#pragma unroll
    for (int j = 0; j < 2; ++j) {
      int nl = wn + j*16 + l16;
      float bs = bias[bn + nl];
#pragma unroll
      for (int r = 0; r < 4; ++r)
        T[nl][wm + i*16 + quad*4 + r] = acc[i][j][r] + bs;
    }
  __syncthreads();
  int t = threadIdx.x;
  int nl = t >> 2, m4 = (t & 3) * 16;
  int bb = bm / SKV, skv0 = bm % SKV;
  short* dst = vT + ((size_t)bb * 256 + bn + nl) * 512 + skv0 + m4;
  bf16x8 o0, o1;
#pragma unroll
  for (int ii = 0; ii < 8; ++ii) o0[ii] = (short)f2b(T[nl][m4 + ii]);
#pragma unroll
  for (int ii = 0; ii < 8; ++ii) o1[ii] = (short)f2b(T[nl][m4 + 8 + ii]);
  *(bf16x8*)dst = o0;
  *(bf16x8*)(dst + 8) = o1;
}

// ---------------- O projection: out fp32 = A@W + bias + residin ----------------
__global__ __launch_bounds__(256) void proj_o_mfma(const short* __restrict__ A,
                                                   const short* __restrict__ Wt,
                                                   const float* __restrict__ bias,
                                                   const float* __restrict__ rin,
                                                   float* __restrict__ C, int N, int K) {
  int bn = blockIdx.x * 64, bm = blockIdx.y * 64;
  int lane = threadIdx.x & 63, wv = threadIdx.x >> 6;
  int wm = (wv & 1) * 32, wn = (wv >> 1) * 32;
  int quad = lane >> 4, l16 = lane & 15;
  f32x4 z4 = {0.f,0.f,0.f,0.f};
  f32x4 acc[2][2] = {{z4,z4},{z4,z4}};
  const short* a0p = A + (size_t)(bm + wm + l16) * K;
  const short* a1p = a0p + (size_t)16 * K;
  const short* w0p = Wt + (size_t)(bn + wn + l16) * K;
  const short* w1p = w0p + (size_t)16 * K;
#pragma unroll 2
  for (int k0 = 0; k0 < K; k0 += 32) {
    int ka = k0 + quad * 8;
    bf16x8 a0 = *(const bf16x8*)(a0p + ka);
    bf16x8 a1 = *(const bf16x8*)(a1p + ka);
    bf16x8 b0 = *(const bf16x8*)(w0p + ka);
    bf16x8 b1 = *(const bf16x8*)(w1p + ka);
    acc[0][0] = MFMA(a0, b0, acc[0][0]);
    acc[0][1] = MFMA(a0, b1, acc[0][1]);
    acc[1][0] = MFMA(a1, b0, acc[1][0]);
    acc[1][1] = MFMA(a1, b1, acc[1][1]);
  }
#pragma unroll
  for (int i = 0; i < 2; ++i)
#pragma unroll
    for (int j = 0; j < 2; ++j) {
      int n = bn + wn + j*16 + l16;
      float bs = bias[n];
#pragma unroll
      for (int r = 0; r < 4; ++r) {
        int m = bm + wm + i*16 + quad*4 + r;
        C[(size_t)m * N + n] = acc[i][j][r] + bs + rin[(size_t)m * N + n];
      }
    }
}

// ---------------- QK^T + mask -> fp32 scores ----------------
__global__ __launch_bounds__(256) void qk_mfma(const short* __restrict__ Q,
                                               const short* __restrict__ Kb,
                                               const float* __restrict__ mask,
                                               float* __restrict__ sc,
                                               int b0, int SKV) {
  int z = blockIdx.z, zb = z >> 4, h = z & 15, b = b0 + zb, kvh = h >> 2;
  int bk = blockIdx.x * 64, bq = blockIdx.y * 64;
  int lane = threadIdx.x & 63, wv = threadIdx.x >> 6;
  int wm = (wv & 1) * 32, wn = (wv >> 1) * 32;
  int quad = lane >> 4, l16 = lane & 15;
  f32x4 z4 = {0.f,0.f,0.f,0.f};
  f32x4 acc[2][2] = {{z4,z4},{z4,z4}};
  const short* q0 = Q + (size_t)(b*S_ + bq + wm + l16) * D_ + h * HD_;
  const short* q1 = q0 + (size_t)16 * D_;
  const short* k0p = Kb + (size_t)(b*SKV + bk + wn + l16) * (NKV_*HD_) + kvh * HD_;
  const short* k1p = k0p + (size_t)16 * (NKV_*HD_);
#pragma unroll
  for (int d0 = 0; d0 < HD_; d0 += 32) {
    int ka = d0 + quad * 8;
    bf16x8 a0 = *(const bf16x8*)(q0 + ka);
    bf16x8 a1 = *(const bf16x8*)(q1 + ka);
    bf16x8 b0f = *(const bf16x8*)(k0p + ka);
    bf16x8 b1f = *(const bf16x8*)(k1p + ka);
    acc[0][0] = MFMA(a0, b0f, acc[0][0]);
    acc[0][1] = MFMA(a0, b1f, acc[0][1]);
    acc[1][0] = MFMA(a1, b0f, acc[1][0]);
    acc[1][1] = MFMA(a1, b1f, acc[1][1]);
  }
#pragma unroll
  for (int i = 0; i < 2; ++i)
#pragma unroll
    for (int j = 0; j < 2; ++j) {
      int n = bk + wn + j*16 + l16;
#pragma unroll
      for (int r = 0; r < 4; ++r) {
        int m = bq + wm + i*16 + quad*4 + r;
        sc[((size_t)(zb*NH_ + h) * S_ + m) * SKV + n] =
            acc[i][j][r] + mask[((size_t)(b*S_ + m)) * SKV + n];
      }
    }
}

// ---------------- row softmax: fp32 scores in, bf16 P out (in place) ----------------
__global__ __launch_bounds__(256) void softmax_kernel(float* __restrict__ sc, int SKV, int nrows) {
  int row = blockIdx.x * 4 + (threadIdx.x >> 6);
  int lane = threadIdx.x & 63;
  if (row >= nrows) return;
  float* rp = sc + (size_t)row * SKV;
  short* sp = (short*)rp;
  float4 v[2];
  int nc = SKV >> 8;
  float mx = -1e30f;
#pragma unroll
  for (int c = 0; c < 2; ++c)
    if (c < nc) {
      v[c] = *(float4*)(rp + c*256 + lane*4);
      mx = fmaxf(mx, fmaxf(fmaxf(v[c].x, v[c].y), fmaxf(v[c].z, v[c].w)));
    }
#pragma unroll
  for (int m = 32; m > 0; m >>= 1) mx = fmaxf(mx, __shfl_xor(mx, m, 64));
  float ls = 0.f;
#pragma unroll
  for (int c = 0; c < 2; ++c)
    if (c < nc) {
      v[c].x = __expf(v[c].x - mx); v[c].y = __expf(v[c].y - mx);
      v[c].z = __expf(v[c].z - mx); v[c].w = __expf(v[c].w - mx);
      ls += v[c].x + v[c].y + v[c].z + v[c].w;
    }
#pragma unroll
  for (int m = 32; m > 0; m >>= 1) ls += __shfl_xor(ls, m, 64);
  float inv = 1.0f / ls;
#pragma unroll
  for (int c = 0; c < 2; ++c)
    if (c < nc) {
      s4 o;
      o.x = (short)f2b(v[c].x * inv); o.y = (short)f2b(v[c].y * inv);
      o.z = (short)f2b(v[c].z * inv); o.w = (short)f2b(v[c].w * inv);
      *(s4*)(sp + c*256 + lane*4) = o;
    }
}

// ---------------- P @ V -> attn out bf16 [b*S+q][h*64+d] ----------------
__global__ __launch_bounds__(256) void pv_mfma(const short* __restrict__ Pb,
                                               const short* __restrict__ vT,
                                               short* __restrict__ ob,
                                               int b0, int SKV) {
  int z = blockIdx.y, zb = z >> 4, h = z & 15, b = b0 + zb, kvh = h >> 2;
  int bq = blockIdx.x * 64;
  int lane = threadIdx.x & 63, wv = threadIdx.x >> 6;
  int wm = (wv & 1) * 32, wn = (wv >> 1) * 32;
  int quad = lane >> 4, l16 = lane & 15;
  f32x4 z4 = {0.f,0.f,0.f,0.f};
  f32x4 acc[2][2] = {{z4,z4},{z4,z4}};
  const short* p0 = Pb + ((size_t)(zb*NH_ + h) * S_ + bq + wm + l16) * (size_t)(2*SKV);
  const short* p1 = p0 + (size_t)16 * 2 * SKV;
  const short* v0 = vT + ((size_t)b * 256 + kvh*64 + wn + l16) * 512;
  const short* v1 = v0 + (size_t)16 * 512;
#pragma unroll 4
  for (int k0 = 0; k0 < SKV; k0 += 32) {
    int ka = k0 + quad * 8;
    bf16x8 a0 = *(const bf16x8*)(p0 + ka);
    bf16x8 a1 = *(const bf16x8*)(p1 + ka);
    bf16x8 b0f = *(const bf16x8*)(v0 + ka);
    bf16x8 b1f = *(const bf16x8*)(v1 + ka);
    acc[0][0] = MFMA(a0, b0f, acc[0][0]);
    acc[0][1] = MFMA(a0, b1f, acc[0][1]);
    acc[1][0] = MFMA(a1, b0f, acc[1][0]);
    acc[1][1] = MFMA(a1, b1f, acc[1][1]);
  }
#pragma unroll
  for (int i = 0; i < 2; ++i)
#pragma unroll
    for (int j = 0; j < 2; ++j) {
      int n = wn + j*16 + l16;
#pragma unroll
      for (int r = 0; r < 4; ++r) {
        int m = bq + wm + i*16 + quad*4 + r;
        ob[(size_t)(b*S_ + m) * D_ + h*HD_ + n] = (short)f2b(acc[i][j][r]);
      }
    }
}

// ---------------- MoE gate, LDS-staged 2-phase: H = bf16(gelu(x@W1e) * (x@W3e)) ----------------
// tile 64(M) x 128(N), BK=32, 4 waves (each 32x64), double-buffered LDS via global_load_lds.
__global__ __launch_bounds__(256) void moe_gate_mfma(const short* __restrict__ xlnb,
                                                     const short* __restrict__ w1t,
                                                     const short* __restrict__ w3t,
                                                     short* __restrict__ Hs,
                                                     const float* __restrict__ coef,
                                                     const int* __restrict__ slot) {
  int e = blockIdx.z;
  int bn = blockIdx.x * 128, bm = blockIdx.y * 64;
  int b = bm >> 8;
  if (coef[e * B_ + b] == 0.0f) return;     // block-uniform: safe before barriers
  int sl = slot[e * B_ + b];
  int lane = threadIdx.x & 63, wv = threadIdx.x >> 6;
  int wm = (wv & 1) * 32, wn = (wv >> 1) * 64;
  int quad = lane >> 4, l16 = lane & 15;
  int r4 = lane >> 2, c4 = lane & 3;        // staging: row-in-seg, 16B chunk

  __shared__ short ldsA[2][64 * 32];        // [row][k] 64B rows
  __shared__ short ldsB1[2][128 * 32];
  __shared__ short ldsB3[2][128 * 32];

  size_t eoff = (size_t)e * D_ * DE_;
  // per-lane global srcs (wave wv stages A-seg wv, B-segs 2wv,2wv+1)
  const short* gA  = xlnb + (size_t)(bm + wv * 16 + r4) * D_ + c4 * 8;
  const short* gB1 = w1t + eoff + (size_t)(bn + wv * 32 + r4) * D_ + c4 * 8;
  const short* gB3 = w3t + eoff + (size_t)(bn + wv * 32 + r4) * D_ + c4 * 8;

  f32x4 z4 = {0.f,0.f,0.f,0.f};
  f32x4 acc1[2][4] = {{z4,z4,z4,z4},{z4,z4,z4,z4}};
  f32x4 acc3[2][4] = {{z4,z4,z4,z4},{z4,z4,z4,z4}};

#define GATE_STAGE(cc, k0)                                                              \
  do {                                                                                  \
    __builtin_amdgcn_global_load_lds(gA + (k0),                 &ldsA[cc][wv*512], 16, 0, 0);  \
    __builtin_amdgcn_global_load_lds(gB1 + (k0),                &ldsB1[cc][wv*1024], 16, 0, 0);\
    __builtin_amdgcn_global_load_lds(gB1 + (size_t)16*D_ + (k0), &ldsB1[cc][wv*1024+512], 16, 0, 0);\
    __builtin_amdgcn_global_load_lds(gB3 + (k0),                &ldsB3[cc][wv*1024], 16, 0, 0);\
    __builtin_amdgcn_global_load_lds(gB3 + (size_t)16*D_ + (k0), &ldsB3[cc][wv*1024+512], 16, 0, 0);\
  } while (0)

#define GATE_COMP(cc)                                                                   \
  do {                                                                                  \
    bf16x8 a[2], f1[4], f3[4];                                                          \
    a[0] = *(const bf16x8*)&ldsA[cc][(wm + l16) * 32 + quad * 8];                       \
    a[1] = *(const bf16x8*)&ldsA[cc][(wm + 16 + l16) * 32 + quad * 8];                  \
    _Pragma("unroll")                                                                   \
    for (int ni = 0; ni < 4; ++ni) {                                                    \
      f1[ni] = *(const bf16x8*)&ldsB1[cc][(wn + ni*16 + l16) * 32 + quad * 8];          \
      f3[ni] = *(const bf16x8*)&ldsB3[cc][(wn + ni*16 + l16) * 32 + quad * 8];          \
    }                                                                                   \
    _Pragma("unroll")                                                                   \
    for (int mi = 0; mi < 2; ++mi)                                                      \
      _Pragma("unroll")                                                                 \
      for (int ni = 0; ni < 4; ++ni) {                                                  \
        acc1[mi][ni] = MFMA(a[mi], f1[ni], acc1[mi][ni]);                               \
        acc3[mi][ni] = MFMA(a[mi], f3[ni], acc3[mi][ni]);                               \
      }                                                                                 \
  } while (0)

  GATE_STAGE(0, 0);
  __syncthreads();
  int cur = 0;
  for (int t = 0; t < (D_ / 32) - 1; ++t) {
    GATE_STAGE(cur ^ 1, (t + 1) * 32);   // async prefetch, hides under compute
    GATE_COMP(cur);
    __syncthreads();                     // drains vmcnt -> next buffer ready, this one reusable
    cur ^= 1;
  }
  GATE_COMP(cur);
#undef GATE_STAGE
#undef GATE_COMP

  short* Hp = Hs + ((size_t)(sl * B_ + b) * S_ + (bm & 255)) * DE_;
#pragma unroll
  for (int mi = 0; mi < 2; ++mi)
#pragma unroll
    for (int ni = 0; ni < 4; ++ni) {
      int n = bn + wn + ni * 16 + l16;
#pragma unroll
      for (int r = 0; r < 4; ++r) {
        int lm = wm + mi * 16 + quad * 4 + r;
        float c1 = acc1[mi][ni][r], c3 = acc3[mi][ni][r];
        float g = 0.5f * c1 * (1.0f + erff(c1 * 0.70710678118654752f));
        Hp[(size_t)lm * DE_ + n] = (short)f2b(g * c3);
      }
    }
}

// ---------------- MoE down, LDS-staged 2-phase: resid += coef * (H @ W2e), 4-way K-split ----
// tile 64(M) x 128(N), BK=32, z = e*4 + kc.
__global__ __launch_bounds__(256) void moe_down_mfma(const short* __restrict__ Hs,
                                                     const short* __restrict__ w2t,
                                                     float* resid,
                                                     const float* __restrict__ coef,
                                                     const int* __restrict__ slot) {
  int zc = blockIdx.z;
  int e = zc >> 2, kc = zc & 3;
  int bn = blockIdx.x * 128, bm = blockIdx.y * 64;
  int b = bm >> 8;
  float cf = coef[e * B_ + b];
  if (cf == 0.0f) return;
  int sl = slot[e * B_ + b];
  int lane = threadIdx.x & 63, wv = threadIdx.x >> 6;
  int wm = (wv & 1) * 32, wn = (wv >> 1) * 64;
  int quad = lane >> 4, l16 = lane & 15;
  int r4 = lane >> 2, c4 = lane & 3;

  __shared__ short ldsA[2][64 * 32];
  __shared__ short ldsB[2][128 * 32];

  const short* gA = Hs + ((size_t)(sl * B_ + b) * S_ + (bm & 255) + wv * 16 + r4) * DE_
                    + kc * 1024 + c4 * 8;
  const short* gB = w2t + (size_t)e * DE_ * D_ + (size_t)(bn + wv * 32 + r4) * DE_
                    + kc * 1024 + c4 * 8;

  f32x4 z4 = {0.f,0.f,0.f,0.f};
  f32x4 acc[2][4] = {{z4,z4,z4,z4},{z4,z4,z4,z4}};

#define DOWN_STAGE(cc, k0)                                                              \
  do {                                                                                  \
    __builtin_amdgcn_global_load_lds(gA + (k0),                  &ldsA[cc][wv*512], 16, 0, 0); \
    __builtin_amdgcn_global_load_lds(gB + (k0),                  &ldsB[cc][wv*1024], 16, 0, 0);\
    __builtin_amdgcn_global_load_lds(gB + (size_t)16*DE_ + (k0), &ldsB[cc][wv*1024+512], 16, 0, 0);\
  } while (0)

#define DOWN_COMP(cc)                                                                   \
  do {                                                                                  \
    bf16x8 a[2], f[4];                                                                  \
    a[0] = *(const bf16x8*)&ldsA[cc][(wm + l16) * 32 + quad * 8];                       \
    a[1] = *(const bf16x8*)&ldsA[cc][(wm + 16 + l16) * 32 + quad * 8];                  \
    _Pragma("unroll")                                                                   \
    for (int ni = 0; ni < 4; ++ni)                                                      \
      f[ni] = *(const bf16x8*)&ldsB[cc][(wn + ni*16 + l16) * 32 + quad * 8];            \
    _Pragma("unroll")                                                                   \
    for (int mi = 0; mi < 2; ++mi)                                                      \
      _Pragma("unroll")                                                                 \
      for (int ni = 0; ni < 4; ++ni)                                                    \
        acc[mi][ni] = MFMA(a[mi], f[ni], acc[mi][ni]);                                  \
  } while (0)

  DOWN_STAGE(0, 0);
  __syncthreads();
  int cur = 0;
  for (int t = 0; t < 31; ++t) {
    DOWN_STAGE(cur ^ 1, (t + 1) * 32);
    DOWN_COMP(cur);
    __syncthreads();
    cur ^= 1;
  }
  DOWN_COMP(cur);
#undef DOWN_STAGE
#undef DOWN_COMP

#pragma unroll
  for (int mi = 0; mi < 2; ++mi)
#pragma unroll
    for (int ni = 0; ni < 4; ++ni) {
      int n = bn + wn + ni * 16 + l16;
#pragma unroll
      for (int r = 0; r < 4; ++r) {
        int m = bm + wm + mi * 16 + quad * 4 + r;
        atomicAdd(&resid[(size_t)m * D_ + n], cf * acc[mi][ni][r]);
      }
    }
}

// ---------------- MoE routing coefficients + slots + per-expert active flags ----------------
__global__ void coef_kernel(const int* __restrict__ langs, float* __restrict__ coef,
                            int* __restrict__ slot, int* __restrict__ eact) {
  int t = threadIdx.x;
  if (t < NE_ * B_) {
    int e = t >> 2, b = t & 3;
    int l0 = langs[b*2], l1 = langs[b*2 + 1];
    int counts = (l0 > 3) + (l1 > 3);
    float rw = (counts == 0) ? 1.0f : 1.0f / (float)counts;
    bool m = (l0 == 4 + e) || (l1 == 4 + e);
    coef[t] = m ? rw : 0.0f;
    int s = 0;
    for (int ep = 0; ep < e; ++ep) s += ((l0 == 4 + ep) || (l1 == 4 + ep)) ? 1 : 0;
    slot[t] = s;
  }
  if (t < NE_) {
    int any = 0;
    for (int b = 0; b < B_; ++b) {
      int l0 = langs[b*2], l1 = langs[b*2 + 1];
      any |= (l0 == 4 + t) || (l1 == 4 + t);
    }
    eact[t] = any;
  }
}

extern "C" void kernel_launch(void* const* d_in, const int* in_sizes, int n_in,
                              void* d_out, int out_size, void* d_ws, size_t ws_size,
                              hipStream_t stream) {
  const float* hidden = (const float*)d_in[0];
  const float* enc    = (const float*)d_in[1];
  const float* amask  = (const float*)d_in[2];
  const float* emask  = (const float*)d_in[3];
  const int*   langs  = (const int*)d_in[4];
  const float* ln1g = (const float*)d_in[5];
  const float* ln1b = (const float*)d_in[6];
  const float* saqw = (const float*)d_in[7];
  const float* saqb = (const float*)d_in[8];
  const float* sakw = (const float*)d_in[9];
  const float* sakb = (const float*)d_in[10];
  const float* savw = (const float*)d_in[11];
  const float* savb = (const float*)d_in[12];
  const float* saow = (const float*)d_in[13];
  const float* saob = (const float*)d_in[14];
  const float* ln2g = (const float*)d_in[15];
  const float* ln2b = (const float*)d_in[16];
  const float* caqw = (const float*)d_in[17];
  const float* caqb = (const float*)d_in[18];
  const float* cakw = (const float*)d_in[19];
  const float* cakb = (const float*)d_in[20];
  const float* cavw = (const float*)d_in[21];
  const float* cavb = (const float*)d_in[22];
  const float* caow = (const float*)d_in[23];
  const float* caob = (const float*)d_in[24];
  const float* ln3g = (const float*)d_in[25];
  const float* ln3b = (const float*)d_in[26];
  const float* w1   = (const float*)d_in[27];
  const float* w2   = (const float*)d_in[28];
  const float* w3   = (const float*)d_in[29];

  float* resid = (float*)d_out;     // fp32 residual stream lives in d_out

  const int M = B_ * S_;            // 1024
  float* ws = (float*)d_ws;
  short* xlnb = (short*)ws;  ws += (M * D_) / 2;          //    2 MB
  short* encb = (short*)ws;  ws += (B_ * SK_ * D_) / 2;   //    4 MB
  short* qb   = (short*)ws;  ws += (M * D_) / 2;          //    2 MB
  short* kb   = (short*)ws;  ws += (B_ * SK_ * 256) / 2;  //    1 MB
  short* vT   = (short*)ws;  ws += (B_ * 256 * 512) / 2;  //    1 MB
  short* ab   = (short*)ws;  ws += (M * D_) / 2;          //    2 MB
  float* scb  = ws;          ws += B_ * NH_ * S_ * SK_;   // 33.5 MB (scores all 4 batches / MoE-H alias)
  float* coef = ws;          ws += 32;
  int*   slot = (int*)ws;    ws += 32;
  int*   eact = (int*)ws;    ws += 32;
  // bf16 transposed weights
  short* saqt = (short*)ws;  ws += (D_ * D_) / 2;
  short* sakt = (short*)ws;  ws += (D_ * 256) / 2;
  short* savt = (short*)ws;  ws += (D_ * 256) / 2;
  short* saot = (short*)ws;  ws += (D_ * D_) / 2;
  short* caqt = (short*)ws;  ws += (D_ * D_) / 2;
  short* cakt = (short*)ws;  ws += (D_ * 256) / 2;
  short* cavt = (short*)ws;  ws += (D_ * 256) / 2;
  short* caot = (short*)ws;  ws += (D_ * D_) / 2;        // attn weights total ~10 MB
  short* w1t  = (short*)ws;  ws += (size_t)NE_ * D_ * DE_ / 2;  // 64 MB (all experts)
  short* w3t  = (short*)ws;  ws += (size_t)NE_ * D_ * DE_ / 2;  // 64 MB
  short* w2t  = (short*)ws;  ws += (size_t)NE_ * D_ * DE_ / 2;  // 64 MB  — total ~250 MB (ws is 512 MB)
  short* Hs   = (short*)scb;                              // MoE hidden [2 slots][B][S][DE] bf16 = 16 MB

  dim3 blk(256);

  // ---- weight transpose-convert (attention) ----
  P8 p;
  p.s[0] = saqw; p.d[0] = saqt; p.n[0] = D_;
  p.s[1] = sakw; p.d[1] = sakt; p.n[1] = 256;
  p.s[2] = savw; p.d[2] = savt; p.n[2] = 256;
  p.s[3] = saow; p.d[3] = saot; p.n[3] = D_;
  p.s[4] = caqw; p.d[4] = caqt; p.n[4] = D_;
  p.s[5] = cakw; p.d[5] = cakt; p.n[5] = 256;
  p.s[6] = cavw; p.d[6] = cavt; p.n[6] = 256;
  p.s[7] = caow; p.d[7] = caot; p.n[7] = D_;
  tconv_attn<<<dim3(16, 16, 8), blk, 0, stream>>>(p);
  coef_kernel<<<1, 64, 0, stream>>>(langs, coef, slot, eact);
  // MoE weight transpose for all active experts (one launch)
  tconv_moe<<<dim3(64, 16, NE_ * 3), blk, 0, stream>>>(w1, w3, w2, w1t, w3t, w2t, eact);

  // ---- self attention ----
  ln_kernel<<<M, blk, 0, stream>>>(hidden, ln1g, ln1b, xlnb);
  proj_mfma<<<dim3(16, 16), blk, 0, stream>>>(xlnb, saqt, saqb, qb, 0.125f, D_, D_);
  proj_mfma<<<dim3(4, 16), blk, 0, stream>>>(xlnb, sakt, sakb, kb, 1.0f, 256, D_);
  proj_v_mfma<<<dim3(4, 16), blk, 0, stream>>>(xlnb, savt, savb, vT, 256, D_);
  qk_mfma<<<dim3(4, 4, 4*NH_), blk, 0, stream>>>(qb, kb, amask, scb, 0, S_);
  softmax_kernel<<<(4*NH_*S_)/4, blk, 0, stream>>>(scb, S_, 4*NH_*S_);
  pv_mfma<<<dim3(4, 4*NH_), blk, 0, stream>>>((short*)scb, vT, ab, 0, S_);
  proj_o_mfma<<<dim3(16, 16), blk, 0, stream>>>(ab, saot, saob, hidden, resid, D_, D_);

  // ---- cross attention (all 4 batches in one pass) ----
  ln_kernel<<<M, blk, 0, stream>>>(resid, ln2g, ln2b, xlnb);
  proj_mfma<<<dim3(16, 16), blk, 0, stream>>>(xlnb, caqt, caqb, qb, 0.125f, D_, D_);
  cast_f2b<<<(B_*SK_*D_)/1024, blk, 0, stream>>>(enc, encb, B_*SK_*D_);
  proj_mfma<<<dim3(4, 32), blk, 0, stream>>>(encb, cakt, cakb, kb, 1.0f, 256, D_);
  proj_v_mfma<<<dim3(4, 32), blk, 0, stream>>>(encb, cavt, cavb, vT, 512, D_);
  qk_mfma<<<dim3(8, 4, 4*NH_), blk, 0, stream>>>(qb, kb, emask, scb, 0, SK_);
  softmax_kernel<<<(4*NH_*S_)/4, blk, 0, stream>>>(scb, SK_, 4*NH_*S_);
  pv_mfma<<<dim3(4, 4*NH_), blk, 0, stream>>>((short*)scb, vT, ab, 0, SK_);
  proj_o_mfma<<<dim3(16, 16), blk, 0, stream>>>(ab, caot, caob, resid, resid, D_, D_);

  // ---- MoE (all experts parallel, LDS-staged GEMMs) ----
  ln_kernel<<<M, blk, 0, stream>>>(resid, ln3g, ln3b, xlnb);
  moe_gate_mfma<<<dim3(DE_/128, M/64, NE_), blk, 0, stream>>>(xlnb, w1t, w3t, Hs, coef, slot);
  moe_down_mfma<<<dim3(D_/128, M/64, NE_*4), blk, 0, stream>>>(Hs, w2t, resid, coef, slot);
}

// Round 10
// 725.370 us; speedup vs baseline: 1.3829x; 1.0055x over previous
//
#include <hip/hip_runtime.h>
#include <math.h>

#define B_   4
#define S_   256
#define SK_  512
#define D_   1024
#define NH_  16
#define NKV_ 4
#define HD_  64
#define DE_  4096
#define NE_  8

typedef __attribute__((ext_vector_type(8))) short bf16x8;
typedef __attribute__((ext_vector_type(4))) float f32x4;

struct __align__(8) s4 { short x, y, z, w; };

#define MFMA(a,b,c) __builtin_amdgcn_mfma_f32_16x16x32_bf16(a,b,c,0,0,0)

__device__ __forceinline__ unsigned short f2b(float f) {  // RNE
  union { float f; unsigned u; } v; v.f = f;
  unsigned r = v.u + 0x7FFF + ((v.u >> 16) & 1);
  return (unsigned short)(r >> 16);
}

__device__ __forceinline__ unsigned short f2bh(float f) {  // round-half-up (matches old weight path)
  return (unsigned short)((__float_as_uint(f) + 0x8000u) >> 16);
}

// ---------------- transpose-convert: fp32 W[K][N] -> bf16 Wt[N][K], one 64x64 tile/block ----
__device__ __forceinline__ void tconv_tile(float (*T)[65],
                                           const float* __restrict__ W,
                                           short* __restrict__ Wt,
                                           int N, int K, int n0, int k0) {
  int t = threadIdx.x;
  int kk = t >> 4, n4 = (t & 15) * 4;
#pragma unroll
  for (int it = 0; it < 4; ++it) {
    float4 v = *(const float4*)(W + (size_t)(k0 + kk + 16 * it) * N + n0 + n4);
    T[kk + 16 * it][n4 + 0] = v.x;
    T[kk + 16 * it][n4 + 1] = v.y;
    T[kk + 16 * it][n4 + 2] = v.z;
    T[kk + 16 * it][n4 + 3] = v.w;
  }
  __syncthreads();
  int n = t >> 2, kb = (t & 3) * 16;
  bf16x8 o0, o1;
#pragma unroll
  for (int j = 0; j < 8; ++j) o0[j] = (short)f2bh(T[kb + j][n]);
#pragma unroll
  for (int j = 0; j < 8; ++j) o1[j] = (short)f2bh(T[kb + 8 + j][n]);
  short* dst = Wt + (size_t)(n0 + n) * K + k0 + kb;
  *(bf16x8*)dst = o0;
  *(bf16x8*)(dst + 8) = o1;
}

struct P8 {
  const float* s[8];
  short* d[8];
  int n[8];
};

// all 8 attention weights (K = D_ = 1024 for each); z picks the matrix
__global__ __launch_bounds__(256) void tconv_attn(P8 p) {
  int z = blockIdx.z;
  int N = p.n[z];
  if ((int)blockIdx.x * 64 >= N) return;
  __shared__ float T[64][65];
  tconv_tile(T, p.s[z], p.d[z], N, D_, blockIdx.x * 64, blockIdx.y * 64);
}

// ALL experts in one launch: z = e*3 + m; m=0:w1, m=1:w3 ([1024][4096] -> [4096][1024]),
// m=2: w2 ([4096][1024] -> [1024][4096]). Inactive experts exit. (R5-verified version.)
__global__ __launch_bounds__(256) void tconv_moe(const float* __restrict__ w1,
                                                 const float* __restrict__ w3,
                                                 const float* __restrict__ w2,
                                                 short* __restrict__ w1t,
                                                 short* __restrict__ w3t,
                                                 short* __restrict__ w2t,
                                                 const int* __restrict__ eact) {
  int z = blockIdx.z;
  int e = z / 3, m = z - e * 3;
  if (!eact[e]) return;
  __shared__ float T[64][65];
  size_t off = (size_t)e * D_ * DE_;
  if (m == 0) {
    tconv_tile(T, w1 + off, w1t + off, DE_, D_, blockIdx.x * 64, blockIdx.y * 64);
  } else if (m == 1) {
    tconv_tile(T, w3 + off, w3t + off, DE_, D_, blockIdx.x * 64, blockIdx.y * 64);
  } else {
    int lin = blockIdx.y * 64 + blockIdx.x;       // 0..1023
    int nt = lin & 15, kt = lin >> 4;             // N=1024 -> 16 n-tiles, K=4096 -> 64 k-tiles
    tconv_tile(T, w2 + off, w2t + off, D_, DE_, nt * 64, kt * 64);
  }
}

// ---------------- layernorm: fp32 in, bf16 out ----------------
__global__ __launch_bounds__(256) void ln_kernel(const float* __restrict__ x,
                                                 const float* __restrict__ g,
                                                 const float* __restrict__ be,
                                                 short* __restrict__ y) {
  int row = blockIdx.x, tid = threadIdx.x;
  const float4 v = ((const float4*)(x + (size_t)row * D_))[tid];
  float s  = v.x + v.y + v.z + v.w;
  float s2 = v.x*v.x + v.y*v.y + v.z*v.z + v.w*v.w;
  __shared__ float r1[256], r2[256];
  r1[tid] = s; r2[tid] = s2; __syncthreads();
  for (int off = 128; off > 0; off >>= 1) {
    if (tid < off) { r1[tid] += r1[tid+off]; r2[tid] += r2[tid+off]; }
    __syncthreads();
  }
  float mean = r1[0] * (1.0f / D_);
  float var  = r2[0] * (1.0f / D_) - mean * mean;
  float inv  = rsqrtf(var + 1e-5f);
  int c = tid * 4;
  s4 o;
  o.x = (short)f2b((v.x - mean) * inv * g[c]   + be[c]);
  o.y = (short)f2b((v.y - mean) * inv * g[c+1] + be[c+1]);
  o.z = (short)f2b((v.z - mean) * inv * g[c+2] + be[c+2]);
  o.w = (short)f2b((v.w - mean) * inv * g[c+3] + be[c+3]);
  *(s4*)(y + (size_t)row * D_ + c) = o;
}

// ---------------- cast fp32 -> bf16 ----------------
__global__ void cast_f2b(const float* __restrict__ in, short* __restrict__ out, int n) {
  int i = (blockIdx.x * 256 + threadIdx.x) * 4;
  if (i < n) {
    float4 v = *(const float4*)(in + i);
    s4 o; o.x=(short)f2b(v.x); o.y=(short)f2b(v.y); o.z=(short)f2b(v.z); o.w=(short)f2b(v.w);
    *(s4*)(out + i) = o;
  }
}

// ---------------- projection (direct loads, used for K/V): Cb = bf16((A@W + bias)*scale) ----
__global__ __launch_bounds__(256) void proj_mfma(const short* __restrict__ A,
                                                 const short* __restrict__ Wt,
                                                 const float* __restrict__ bias,
                                                 short* __restrict__ Cb,
                                                 float scale, int N, int K) {
  int bn = blockIdx.x * 64, bm = blockIdx.y * 64;
  int lane = threadIdx.x & 63, wv = threadIdx.x >> 6;
  int wm = (wv & 1) * 32, wn = (wv >> 1) * 32;
  int quad = lane >> 4, l16 = lane & 15;
  f32x4 z4 = {0.f,0.f,0.f,0.f};
  f32x4 acc[2][2] = {{z4,z4},{z4,z4}};
  const short* a0p = A + (size_t)(bm + wm + l16) * K;
  const short* a1p = a0p + (size_t)16 * K;
  const short* w0p = Wt + (size_t)(bn + wn + l16) * K;
  const short* w1p = w0p + (size_t)16 * K;
#pragma unroll 2
  for (int k0 = 0; k0 < K; k0 += 32) {
    int ka = k0 + quad * 8;
    bf16x8 a0 = *(const bf16x8*)(a0p + ka);
    bf16x8 a1 = *(const bf16x8*)(a1p + ka);
    bf16x8 b0 = *(const bf16x8*)(w0p + ka);
    bf16x8 b1 = *(const bf16x8*)(w1p + ka);
    acc[0][0] = MFMA(a0, b0, acc[0][0]);
    acc[0][1] = MFMA(a0, b1, acc[0][1]);
    acc[1][0] = MFMA(a1, b0, acc[1][0]);
    acc[1][1] = MFMA(a1, b1, acc[1][1]);
  }
#pragma unroll
  for (int i = 0; i < 2; ++i)
#pragma unroll
    for (int j = 0; j < 2; ++j) {
      int n = bn + wn + j*16 + l16;
      float bs = bias[n];
#pragma unroll
      for (int r = 0; r < 4; ++r) {
        int m = bm + wm + i*16 + quad*4 + r;
        Cb[(size_t)m * N + n] = (short)f2b((acc[i][j][r] + bs) * scale);
      }
    }
}

// ---------------- staged projection (LDS 2-phase, for Q): Cb = bf16((A@W + bias)*scale) ------
__global__ __launch_bounds__(256) void proj_staged(const short* __restrict__ A,
                                                   const short* __restrict__ Wt,
                                                   const float* __restrict__ bias,
                                                   short* __restrict__ Cb,
                                                   float scale, int N, int K) {
  int bn = blockIdx.x * 64, bm = blockIdx.y * 64;
  int lane = threadIdx.x & 63, wv = threadIdx.x >> 6;
  int wm = (wv & 1) * 32, wn = (wv >> 1) * 32;
  int quad = lane >> 4, l16 = lane & 15;
  int r4 = lane >> 2, c4 = lane & 3;
  __shared__ short ldsA[2][64 * 32];
  __shared__ short ldsB[2][64 * 32];
  const short* gA = A  + (size_t)(bm + wv * 16 + r4) * K + c4 * 8;
  const short* gB = Wt + (size_t)(bn + wv * 16 + r4) * K + c4 * 8;
  f32x4 z4 = {0.f,0.f,0.f,0.f};
  f32x4 acc[2][2] = {{z4,z4},{z4,z4}};
#define PSTAGE(cc, k0)                                                                \
  do {                                                                                \
    __builtin_amdgcn_global_load_lds(gA + (k0), &ldsA[cc][wv * 512], 16, 0, 0);       \
    __builtin_amdgcn_global_load_lds(gB + (k0), &ldsB[cc][wv * 512], 16, 0, 0);       \
  } while (0)
#define PCOMP(cc)                                                                     \
  do {                                                                                \
    bf16x8 a0 = *(const bf16x8*)&ldsA[cc][(wm + l16) * 32 + quad * 8];                \
    bf16x8 a1 = *(const bf16x8*)&ldsA[cc][(wm + 16 + l16) * 32 + quad * 8];           \
    bf16x8 b0 = *(const bf16x8*)&ldsB[cc][(wn + l16) * 32 + quad * 8];                \
    bf16x8 b1 = *(const bf16x8*)&ldsB[cc][(wn + 16 + l16) * 32 + quad * 8];           \
    acc[0][0] = MFMA(a0, b0, acc[0][0]);                                              \
    acc[0][1] = MFMA(a0, b1, acc[0][1]);                                              \
    acc[1][0] = MFMA(a1, b0, acc[1][0]);                                              \
    acc[1][1] = MFMA(a1, b1, acc[1][1]);                                              \
  } while (0)
  PSTAGE(0, 0);
  __syncthreads();
  int cur = 0;
  for (int t = 0; t < K / 32 - 1; ++t) {
    PSTAGE(cur ^ 1, (t + 1) * 32);
    PCOMP(cur);
    __syncthreads();
    cur ^= 1;
  }
  PCOMP(cur);
#undef PSTAGE
#undef PCOMP
#pragma unroll
  for (int i = 0; i < 2; ++i)
#pragma unroll
    for (int j = 0; j < 2; ++j) {
      int n = bn + wn + j*16 + l16;
      float bs = bias[n];
#pragma unroll
      for (int r = 0; r < 4; ++r) {
        int m = bm + wm + i*16 + quad*4 + r;
        Cb[(size_t)m * N + n] = (short)f2b((acc[i][j][r] + bs) * scale);
      }
    }
}

// ---------------- staged O projection: out fp32 = A@W + bias + residin ----------------
__global__ __launch_bounds__(256) void proj_o_staged(const short* __restrict__ A,
                                                     const short* __restrict__ Wt,
                                                     const float* __restrict__ bias,
                                                     const float* __restrict__ rin,
                                                     float* __restrict__ C, int N, int K) {
  int bn = blockIdx.x * 64, bm = blockIdx.y * 64;
  int lane = threadIdx.x & 63, wv = threadIdx.x >> 6;
  int wm = (wv & 1) * 32, wn = (wv >> 1) * 32;
  int quad = lane >> 4, l16 = lane & 15;
  int r4 = lane >> 2, c4 = lane & 3;
  __shared__ short ldsA[2][64 * 32];
  __shared__ short ldsB[2][64 * 32];
  const short* gA = A  + (size_t)(bm + wv * 16 + r4) * K + c4 * 8;
  const short* gB = Wt + (size_t)(bn + wv * 16 + r4) * K + c4 * 8;
  f32x4 z4 = {0.f,0.f,0.f,0.f};
  f32x4 acc[2][2] = {{z4,z4},{z4,z4}};
#define PSTAGE(cc, k0)                                                                \
  do {                                                                                \
    __builtin_amdgcn_global_load_lds(gA + (k0), &ldsA[cc][wv * 512], 16, 0, 0);       \
    __builtin_amdgcn_global_load_lds(gB + (k0), &ldsB[cc][wv * 512], 16, 0, 0);       \
  } while (0)
#define PCOMP(cc)                                                                     \
  do {                                                                                \
    bf16x8 a0 = *(const bf16x8*)&ldsA[cc][(wm + l16) * 32 + quad * 8];                \
    bf16x8 a1 = *(const bf16x8*)&ldsA[cc][(wm + 16 + l16) * 32 + quad * 8];           \
    bf16x8 b0 = *(const bf16x8*)&ldsB[cc][(wn + l16) * 32 + quad * 8];                \
    bf16x8 b1 = *(const bf16x8*)&ldsB[cc][(wn + 16 + l16) * 32 + quad * 8];           \
    acc[0][0] = MFMA(a0, b0, acc[0][0]);                                              \
    acc[0][1] = MFMA(a0, b1, acc[0][1]);                                              \
    acc[1][0] = MFMA(a1, b0, acc[1][0]);                                              \
    acc[1][1] = MFMA(a1, b1, acc[1][1]);                                              \
  } while (0)
  PSTAGE(0, 0);
  __syncthreads();
  int cur = 0;
  for (int t = 0; t < K / 32 - 1; ++t) {
    PSTAGE(cur ^ 1, (t + 1) * 32);
    PCOMP(cur);
    __syncthreads();
    cur ^= 1;
  }
  PCOMP(cur);
#undef PSTAGE
#undef PCOMP
#pragma unroll
  for (int i = 0; i < 2; ++i)
#pragma unroll
    for (int j = 0; j < 2; ++j) {
      int n = bn + wn + j*16 + l16;
      float bs = bias[n];
#pragma unroll
      for (int r = 0; r < 4; ++r) {
        int m = bm + wm + i*16 + quad*4 + r;
        C[(size_t)m * N + n] = acc[i][j][r] + bs + rin[(size_t)m * N + n];
      }
    }
}

// ---------------- V projection with transposed output: vT[b][256 d][512 skv] ----------------
__global__ __launch_bounds__(256) void proj_v_mfma(const short* __restrict__ A,
                                                   const short* __restrict__ Wt,
                                                   const float* __restrict__ bias,
                                                   short* __restrict__ vT,
                                                   int SKV, int K) {
  int bn = blockIdx.x * 64, bm = blockIdx.y * 64;
  int lane = threadIdx.x & 63, wv = threadIdx.x >> 6;
  int wm = (wv & 1) * 32, wn = (wv >> 1) * 32;
  int quad = lane >> 4, l16 = lane & 15;
  f32x4 z4 = {0.f,0.f,0.f,0.f};
  f32x4 acc[2][2] = {{z4,z4},{z4,z4}};
  const short* a0p = A + (size_t)(bm + wm + l16) * K;
  const short* a1p = a0p + (size_t)16 * K;
  const short* w0p = Wt + (size_t)(bn + wn + l16) * K;
  const short* w1p = w0p + (size_t)16 * K;
#pragma unroll 2
  for (int k0 = 0; k0 < K; k0 += 32) {
    int ka = k0 + quad * 8;
    bf16x8 a0 = *(const bf16x8*)(a0p + ka);
    bf16x8 a1 = *(const bf16x8*)(a1p + ka);
    bf16x8 b0 = *(const bf16x8*)(w0p + ka);
    bf16x8 b1 = *(const bf16x8*)(w1p + ka);
    acc[0][0] = MFMA(a0, b0, acc[0][0]);
    acc[0][1] = MFMA(a0, b1, acc[0][1]);
    acc[1][0] = MFMA(a1, b0, acc[1][0]);
    acc[1][1] = MFMA(a1, b1, acc[1][1]);
  }
  __shared__ float T[64][65];
#pragma unroll
  for (int i = 0; i < 2; ++i)
#pragma unroll
    for (int j = 0; j < 2; ++j) {
      int nl = wn + j*16 + l16;
      float bs = bias[bn + nl];
#pragma unroll
      for (int r = 0; r < 4; ++r)
        T[nl][wm + i*16 + quad*4 + r] = acc[i][j][r] + bs;
    }
  __syncthreads();
  int t = threadIdx.x;
  int nl = t >> 2, m4 = (t & 3) * 16;
  int bb = bm / SKV, skv0 = bm % SKV;
  short* dst = vT + ((size_t)bb * 256 + bn + nl) * 512 + skv0 + m4;
  bf16x8 o0, o1;
#pragma unroll
  for (int ii = 0; ii < 8; ++ii) o0[ii] = (short)f2b(T[nl][m4 + ii]);
#pragma unroll
  for (int ii = 0; ii < 8; ++ii) o1[ii] = (short)f2b(T[nl][m4 + 8 + ii]);
  *(bf16x8*)dst = o0;
  *(bf16x8*)(dst + 8) = o1;
}

// ---------------- QK^T + mask -> fp32 scores ----------------
__global__ __launch_bounds__(256) void qk_mfma(const short* __restrict__ Q,
                                               const short* __restrict__ Kb,
                                               const float* __restrict__ mask,
                                               float* __restrict__ sc,
                                               int b0, int SKV) {
  int z = blockIdx.z, zb = z >> 4, h = z & 15, b = b0 + zb, kvh = h >> 2;
  int bk = blockIdx.x * 64, bq = blockIdx.y * 64;
  int lane = threadIdx.x & 63, wv = threadIdx.x >> 6;
  int wm = (wv & 1) * 32, wn = (wv >> 1) * 32;
  int quad = lane >> 4, l16 = lane & 15;
  f32x4 z4 = {0.f,0.f,0.f,0.f};
  f32x4 acc[2][2] = {{z4,z4},{z4,z4}};
  const short* q0 = Q + (size_t)(b*S_ + bq + wm + l16) * D_ + h * HD_;
  const short* q1 = q0 + (size_t)16 * D_;
  const short* k0p = Kb + (size_t)(b*SKV + bk + wn + l16) * (NKV_*HD_) + kvh * HD_;
  const short* k1p = k0p + (size_t)16 * (NKV_*HD_);
#pragma unroll
  for (int d0 = 0; d0 < HD_; d0 += 32) {
    int ka = d0 + quad * 8;
    bf16x8 a0 = *(const bf16x8*)(q0 + ka);
    bf16x8 a1 = *(const bf16x8*)(q1 + ka);
    bf16x8 b0f = *(const bf16x8*)(k0p + ka);
    bf16x8 b1f = *(const bf16x8*)(k1p + ka);
    acc[0][0] = MFMA(a0, b0f, acc[0][0]);
    acc[0][1] = MFMA(a0, b1f, acc[0][1]);
    acc[1][0] = MFMA(a1, b0f, acc[1][0]);
    acc[1][1] = MFMA(a1, b1f, acc[1][1]);
  }
#pragma unroll
  for (int i = 0; i < 2; ++i)
#pragma unroll
    for (int j = 0; j < 2; ++j) {
      int n = bk + wn + j*16 + l16;
#pragma unroll
      for (int r = 0; r < 4; ++r) {
        int m = bq + wm + i*16 + quad*4 + r;
        sc[((size_t)(zb*NH_ + h) * S_ + m) * SKV + n] =
            acc[i][j][r] + mask[((size_t)(b*S_ + m)) * SKV + n];
      }
    }
}

// ---------------- row softmax: fp32 scores in, bf16 P out (in place) ----------------
__global__ __launch_bounds__(256) void softmax_kernel(float* __restrict__ sc, int SKV, int nrows) {
  int row = blockIdx.x * 4 + (threadIdx.x >> 6);
  int lane = threadIdx.x & 63;
  if (row >= nrows) return;
  float* rp = sc + (size_t)row * SKV;
  short* sp = (short*)rp;
  float4 v[2];
  int nc = SKV >> 8;
  float mx = -1e30f;
#pragma unroll
  for (int c = 0; c < 2; ++c)
    if (c < nc) {
      v[c] = *(float4*)(rp + c*256 + lane*4);
      mx = fmaxf(mx, fmaxf(fmaxf(v[c].x, v[c].y), fmaxf(v[c].z, v[c].w)));
    }
#pragma unroll
  for (int m = 32; m > 0; m >>= 1) mx = fmaxf(mx, __shfl_xor(mx, m, 64));
  float ls = 0.f;
#pragma unroll
  for (int c = 0; c < 2; ++c)
    if (c < nc) {
      v[c].x = __expf(v[c].x - mx); v[c].y = __expf(v[c].y - mx);
      v[c].z = __expf(v[c].z - mx); v[c].w = __expf(v[c].w - mx);
      ls += v[c].x + v[c].y + v[c].z + v[c].w;
    }
#pragma unroll
  for (int m = 32; m > 0; m >>= 1) ls += __shfl_xor(ls, m, 64);
  float inv = 1.0f / ls;
#pragma unroll
  for (int c = 0; c < 2; ++c)
    if (c < nc) {
      s4 o;
      o.x = (short)f2b(v[c].x * inv); o.y = (short)f2b(v[c].y * inv);
      o.z = (short)f2b(v[c].z * inv); o.w = (short)f2b(v[c].w * inv);
      *(s4*)(sp + c*256 + lane*4) = o;
    }
}

// ---------------- P @ V -> attn out bf16 [b*S+q][h*64+d] ----------------
__global__ __launch_bounds__(256) void pv_mfma(const short* __restrict__ Pb,
                                               const short* __restrict__ vT,
                                               short* __restrict__ ob,
                                               int b0, int SKV) {
  int z = blockIdx.y, zb = z >> 4, h = z & 15, b = b0 + zb, kvh = h >> 2;
  int bq = blockIdx.x * 64;
  int lane = threadIdx.x & 63, wv = threadIdx.x >> 6;
  int wm = (wv & 1) * 32, wn = (wv >> 1) * 32;
  int quad = lane >> 4, l16 = lane & 15;
  f32x4 z4 = {0.f,0.f,0.f,0.f};
  f32x4 acc[2][2] = {{z4,z4},{z4,z4}};
  const short* p0 = Pb + ((size_t)(zb*NH_ + h) * S_ + bq + wm + l16) * (size_t)(2*SKV);
  const short* p1 = p0 + (size_t)16 * 2 * SKV;
  const short* v0 = vT + ((size_t)b * 256 + kvh*64 + wn + l16) * 512;
  const short* v1 = v0 + (size_t)16 * 512;
#pragma unroll 4
  for (int k0 = 0; k0 < SKV; k0 += 32) {
    int ka = k0 + quad * 8;
    bf16x8 a0 = *(const bf16x8*)(p0 + ka);
    bf16x8 a1 = *(const bf16x8*)(p1 + ka);
    bf16x8 b0f = *(const bf16x8*)(v0 + ka);
    bf16x8 b1f = *(const bf16x8*)(v1 + ka);
    acc[0][0] = MFMA(a0, b0f, acc[0][0]);
    acc[0][1] = MFMA(a0, b1f, acc[0][1]);
    acc[1][0] = MFMA(a1, b0f, acc[1][0]);
    acc[1][1] = MFMA(a1, b1f, acc[1][1]);
  }
#pragma unroll
  for (int i = 0; i < 2; ++i)
#pragma unroll
    for (int j = 0; j < 2; ++j) {
      int n = wn + j*16 + l16;
#pragma unroll
      for (int r = 0; r < 4; ++r) {
        int m = bq + wm + i*16 + quad*4 + r;
        ob[(size_t)(b*S_ + m) * D_ + h*HD_ + n] = (short)f2b(acc[i][j][r]);
      }
    }
}

// ---------------- MoE gate, LDS-staged 2-phase: H = bf16(gelu(x@W1e) * (x@W3e)) ----------------
// tile 64(M) x 128(N), BK=32, 4 waves (each 32x64), double-buffered LDS via global_load_lds.
__global__ __launch_bounds__(256) void moe_gate_mfma(const short* __restrict__ xlnb,
                                                     const short* __restrict__ w1t,
                                                     const short* __restrict__ w3t,
                                                     short* __restrict__ Hs,
                                                     const float* __restrict__ coef,
                                                     const int* __restrict__ slot) {
  int e = blockIdx.z;
  int bn = blockIdx.x * 128, bm = blockIdx.y * 64;
  int b = bm >> 8;
  if (coef[e * B_ + b] == 0.0f) return;     // block-uniform: safe before barriers
  int sl = slot[e * B_ + b];
  int lane = threadIdx.x & 63, wv = threadIdx.x >> 6;
  int wm = (wv & 1) * 32, wn = (wv >> 1) * 64;
  int quad = lane >> 4, l16 = lane & 15;
  int r4 = lane >> 2, c4 = lane & 3;        // staging: row-in-seg, 16B chunk

  __shared__ short ldsA[2][64 * 32];        // [row][k] 64B rows
  __shared__ short ldsB1[2][128 * 32];
  __shared__ short ldsB3[2][128 * 32];

  size_t eoff = (size_t)e * D_ * DE_;
  // per-lane global srcs (wave wv stages A-seg wv, B-segs 2wv,2wv+1)
  const short* gA  = xlnb + (size_t)(bm + wv * 16 + r4) * D_ + c4 * 8;
  const short* gB1 = w1t + eoff + (size_t)(bn + wv * 32 + r4) * D_ + c4 * 8;
  const short* gB3 = w3t + eoff + (size_t)(bn + wv * 32 + r4) * D_ + c4 * 8;

  f32x4 z4 = {0.f,0.f,0.f,0.f};
  f32x4 acc1[2][4] = {{z4,z4,z4,z4},{z4,z4,z4,z4}};
  f32x4 acc3[2][4] = {{z4,z4,z4,z4},{z4,z4,z4,z4}};

#define GATE_STAGE(cc, k0)                                                              \
  do {                                                                                  \
    __builtin_amdgcn_global_load_lds(gA + (k0),                 &ldsA[cc][wv*512], 16, 0, 0);  \
    __builtin_amdgcn_global_load_lds(gB1 + (k0),                &ldsB1[cc][wv*1024], 16, 0, 0);\
    __builtin_amdgcn_global_load_lds(gB1 + (size_t)16*D_ + (k0), &ldsB1[cc][wv*1024+512], 16, 0, 0);\
    __builtin_amdgcn_global_load_lds(gB3 + (k0),                &ldsB3[cc][wv*1024], 16, 0, 0);\
    __builtin_amdgcn_global_load_lds(gB3 + (size_t)16*D_ + (k0), &ldsB3[cc][wv*1024+512], 16, 0, 0);\
  } while (0)

#define GATE_COMP(cc)                                                                   \
  do {                                                                                  \
    bf16x8 a[2], f1[4], f3[4];                                                          \
    a[0] = *(const bf16x8*)&ldsA[cc][(wm + l16) * 32 + quad * 8];                       \
    a[1] = *(const bf16x8*)&ldsA[cc][(wm + 16 + l16) * 32 + quad * 8];                  \
    _Pragma("unroll")                                                                   \
    for (int ni = 0; ni < 4; ++ni) {                                                    \
      f1[ni] = *(const bf16x8*)&ldsB1[cc][(wn + ni*16 + l16) * 32 + quad * 8];          \
      f3[ni] = *(const bf16x8*)&ldsB3[cc][(wn + ni*16 + l16) * 32 + quad * 8];          \
    }                                                                                   \
    _Pragma("unroll")                                                                   \
    for (int mi = 0; mi < 2; ++mi)                                                      \
      _Pragma("unroll")                                                                 \
      for (int ni = 0; ni < 4; ++ni) {                                                  \
        acc1[mi][ni] = MFMA(a[mi], f1[ni], acc1[mi][ni]);                               \
        acc3[mi][ni] = MFMA(a[mi], f3[ni], acc3[mi][ni]);                               \
      }                                                                                  \
  } while (0)

  GATE_STAGE(0, 0);
  __syncthreads();
  int cur = 0;
  for (int t = 0; t < (D_ / 32) - 1; ++t) {
    GATE_STAGE(cur ^ 1, (t + 1) * 32);   // async prefetch, hides under compute
    GATE_COMP(cur);
    __syncthreads();                     // drains vmcnt -> next buffer ready, this one reusable
    cur ^= 1;
  }
  GATE_COMP(cur);
#undef GATE_STAGE
#undef GATE_COMP

  short* Hp = Hs + ((size_t)(sl * B_ + b) * S_ + (bm & 255)) * DE_;
#pragma unroll
  for (int mi = 0; mi < 2; ++mi)
#pragma unroll
    for (int ni = 0; ni < 4; ++ni) {
      int n = bn + wn + ni * 16 + l16;
#pragma unroll
      for (int r = 0; r < 4; ++r) {
        int lm = wm + mi * 16 + quad * 4 + r;
        float c1 = acc1[mi][ni][r], c3 = acc3[mi][ni][r];
        float g = 0.5f * c1 * (1.0f + erff(c1 * 0.70710678118654752f));
        Hp[(size_t)lm * DE_ + n] = (short)f2b(g * c3);
      }
    }
}

// ---------------- MoE down, LDS-staged 2-phase: resid += coef * (H @ W2e), 4-way K-split ----
// tile 64(M) x 128(N), BK=32, z = e*4 + kc.
__global__ __launch_bounds__(256) void moe_down_mfma(const short* __restrict__ Hs,
                                                     const short* __restrict__ w2t,
                                                     float* resid,
                                                     const float* __restrict__ coef,
                                                     const int* __restrict__ slot) {
  int zc = blockIdx.z;
  int e = zc >> 2, kc = zc & 3;
  int bn = blockIdx.x * 128, bm = blockIdx.y * 64;
  int b = bm >> 8;
  float cf = coef[e * B_ + b];
  if (cf == 0.0f) return;
  int sl = slot[e * B_ + b];
  int lane = threadIdx.x & 63, wv = threadIdx.x >> 6;
  int wm = (wv & 1) * 32, wn = (wv >> 1) * 64;
  int quad = lane >> 4, l16 = lane & 15;
  int r4 = lane >> 2, c4 = lane & 3;

  __shared__ short ldsA[2][64 * 32];
  __shared__ short ldsB[2][128 * 32];

  const short* gA = Hs + ((size_t)(sl * B_ + b) * S_ + (bm & 255) + wv * 16 + r4) * DE_
                    + kc * 1024 + c4 * 8;
  const short* gB = w2t + (size_t)e * DE_ * D_ + (size_t)(bn + wv * 32 + r4) * DE_
                    + kc * 1024 + c4 * 8;

  f32x4 z4 = {0.f,0.f,0.f,0.f};
  f32x4 acc[2][4] = {{z4,z4,z4,z4},{z4,z4,z4,z4}};

#define DOWN_STAGE(cc, k0)                                                              \
  do {                                                                                  \
    __builtin_amdgcn_global_load_lds(gA + (k0),                  &ldsA[cc][wv*512], 16, 0, 0); \
    __builtin_amdgcn_global_load_lds(gB + (k0),                  &ldsB[cc][wv*1024], 16, 0, 0);\
    __builtin_amdgcn_global_load_lds(gB + (size_t)16*DE_ + (k0), &ldsB[cc][wv*1024+512], 16, 0, 0);\
  } while (0)

#define DOWN_COMP(cc)                                                                   \
  do {                                                                                  \
    bf16x8 a[2], f[4];                                                                  \
    a[0] = *(const bf16x8*)&ldsA[cc][(wm + l16) * 32 + quad * 8];                       \
    a[1] = *(const bf16x8*)&ldsA[cc][(wm + 16 + l16) * 32 + quad * 8];                  \
    _Pragma("unroll")                                                                   \
    for (int ni = 0; ni < 4; ++ni)                                                      \
      f[ni] = *(const bf16x8*)&ldsB[cc][(wn + ni*16 + l16) * 32 + quad * 8];            \
    _Pragma("unroll")                                                                   \
    for (int mi = 0; mi < 2; ++mi)                                                      \
      _Pragma("unroll")                                                                 \
      for (int ni = 0; ni < 4; ++ni)                                                    \
        acc[mi][ni] = MFMA(a[mi], f[ni], acc[mi][ni]);                                  \
  } while (0)

  DOWN_STAGE(0, 0);
  __syncthreads();
  int cur = 0;
  for (int t = 0; t < 31; ++t) {
    DOWN_STAGE(cur ^ 1, (t + 1) * 32);
    DOWN_COMP(cur);
    __syncthreads();
    cur ^= 1;
  }
  DOWN_COMP(cur);
#undef DOWN_STAGE
#undef DOWN_COMP

#pragma unroll
  for (int mi = 0; mi < 2; ++mi)
#pragma unroll
    for (int ni = 0; ni < 4; ++ni) {
      int n = bn + wn + ni * 16 + l16;
#pragma unroll
      for (int r = 0; r < 4; ++r) {
        int m = bm + wm + mi * 16 + quad * 4 + r;
        atomicAdd(&resid[(size_t)m * D_ + n], cf * acc[mi][ni][r]);
      }
    }
}

// ---------------- MoE routing coefficients + slots + per-expert active flags ----------------
__global__ void coef_kernel(const int* __restrict__ langs, float* __restrict__ coef,
                            int* __restrict__ slot, int* __restrict__ eact) {
  int t = threadIdx.x;
  if (t < NE_ * B_) {
    int e = t >> 2, b = t & 3;
    int l0 = langs[b*2], l1 = langs[b*2 + 1];
    int counts = (l0 > 3) + (l1 > 3);
    float rw = (counts == 0) ? 1.0f : 1.0f / (float)counts;
    bool m = (l0 == 4 + e) || (l1 == 4 + e);
    coef[t] = m ? rw : 0.0f;
    int s = 0;
    for (int ep = 0; ep < e; ++ep) s += ((l0 == 4 + ep) || (l1 == 4 + ep)) ? 1 : 0;
    slot[t] = s;
  }
  if (t < NE_) {
    int any = 0;
    for (int b = 0; b < B_; ++b) {
      int l0 = langs[b*2], l1 = langs[b*2 + 1];
      any |= (l0 == 4 + t) || (l1 == 4 + t);
    }
    eact[t] = any;
  }
}

extern "C" void kernel_launch(void* const* d_in, const int* in_sizes, int n_in,
                              void* d_out, int out_size, void* d_ws, size_t ws_size,
                              hipStream_t stream) {
  const float* hidden = (const float*)d_in[0];
  const float* enc    = (const float*)d_in[1];
  const float* amask  = (const float*)d_in[2];
  const float* emask  = (const float*)d_in[3];
  const int*   langs  = (const int*)d_in[4];
  const float* ln1g = (const float*)d_in[5];
  const float* ln1b = (const float*)d_in[6];
  const float* saqw = (const float*)d_in[7];
  const float* saqb = (const float*)d_in[8];
  const float* sakw = (const float*)d_in[9];
  const float* sakb = (const float*)d_in[10];
  const float* savw = (const float*)d_in[11];
  const float* savb = (const float*)d_in[12];
  const float* saow = (const float*)d_in[13];
  const float* saob = (const float*)d_in[14];
  const float* ln2g = (const float*)d_in[15];
  const float* ln2b = (const float*)d_in[16];
  const float* caqw = (const float*)d_in[17];
  const float* caqb = (const float*)d_in[18];
  const float* cakw = (const float*)d_in[19];
  const float* cakb = (const float*)d_in[20];
  const float* cavw = (const float*)d_in[21];
  const float* cavb = (const float*)d_in[22];
  const float* caow = (const float*)d_in[23];
  const float* caob = (const float*)d_in[24];
  const float* ln3g = (const float*)d_in[25];
  const float* ln3b = (const float*)d_in[26];
  const float* w1   = (const float*)d_in[27];
  const float* w2   = (const float*)d_in[28];
  const float* w3   = (const float*)d_in[29];

  float* resid = (float*)d_out;     // fp32 residual stream lives in d_out

  const int M = B_ * S_;            // 1024
  float* ws = (float*)d_ws;
  short* xlnb = (short*)ws;  ws += (M * D_) / 2;          //    2 MB
  short* encb = (short*)ws;  ws += (B_ * SK_ * D_) / 2;   //    4 MB
  short* qb   = (short*)ws;  ws += (M * D_) / 2;          //    2 MB
  short* kb   = (short*)ws;  ws += (B_ * SK_ * 256) / 2;  //    1 MB
  short* vT   = (short*)ws;  ws += (B_ * 256 * 512) / 2;  //    1 MB
  short* ab   = (short*)ws;  ws += (M * D_) / 2;          //    2 MB
  float* scb  = ws;          ws += B_ * NH_ * S_ * SK_;   // 33.5 MB (scores all 4 batches / MoE-H alias)
  float* coef = ws;          ws += 32;
  int*   slot = (int*)ws;    ws += 32;
  int*   eact = (int*)ws;    ws += 32;
  // bf16 transposed weights
  short* saqt = (short*)ws;  ws += (D_ * D_) / 2;
  short* sakt = (short*)ws;  ws += (D_ * 256) / 2;
  short* savt = (short*)ws;  ws += (D_ * 256) / 2;
  short* saot = (short*)ws;  ws += (D_ * D_) / 2;
  short* caqt = (short*)ws;  ws += (D_ * D_) / 2;
  short* cakt = (short*)ws;  ws += (D_ * 256) / 2;
  short* cavt = (short*)ws;  ws += (D_ * 256) / 2;
  short* caot = (short*)ws;  ws += (D_ * D_) / 2;        // attn weights total ~10 MB
  short* w1t  = (short*)ws;  ws += (size_t)NE_ * D_ * DE_ / 2;  // 64 MB (all experts)
  short* w3t  = (short*)ws;  ws += (size_t)NE_ * D_ * DE_ / 2;  // 64 MB
  short* w2t  = (short*)ws;  ws += (size_t)NE_ * D_ * DE_ / 2;  // 64 MB  — total ~250 MB (ws is 512 MB)
  short* Hs   = (short*)scb;                              // MoE hidden [2 slots][B][S][DE] bf16 = 16 MB

  dim3 blk(256);

  // ---- weight transpose-convert (attention) ----
  P8 p;
  p.s[0] = saqw; p.d[0] = saqt; p.n[0] = D_;
  p.s[1] = sakw; p.d[1] = sakt; p.n[1] = 256;
  p.s[2] = savw; p.d[2] = savt; p.n[2] = 256;
  p.s[3] = saow; p.d[3] = saot; p.n[3] = D_;
  p.s[4] = caqw; p.d[4] = caqt; p.n[4] = D_;
  p.s[5] = cakw; p.d[5] = cakt; p.n[5] = 256;
  p.s[6] = cavw; p.d[6] = cavt; p.n[6] = 256;
  p.s[7] = caow; p.d[7] = caot; p.n[7] = D_;
  tconv_attn<<<dim3(16, 16, 8), blk, 0, stream>>>(p);
  coef_kernel<<<1, 64, 0, stream>>>(langs, coef, slot, eact);
  // MoE weight transpose for all active experts (one launch, R5-verified config)
  tconv_moe<<<dim3(64, 16, NE_ * 3), blk, 0, stream>>>(w1, w3, w2, w1t, w3t, w2t, eact);

  // ---- self attention ----
  ln_kernel<<<M, blk, 0, stream>>>(hidden, ln1g, ln1b, xlnb);
  proj_staged<<<dim3(16, 16), blk, 0, stream>>>(xlnb, saqt, saqb, qb, 0.125f, D_, D_);
  proj_mfma<<<dim3(4, 16), blk, 0, stream>>>(xlnb, sakt, sakb, kb, 1.0f, 256, D_);
  proj_v_mfma<<<dim3(4, 16), blk, 0, stream>>>(xlnb, savt, savb, vT, 256, D_);
  qk_mfma<<<dim3(4, 4, 4*NH_), blk, 0, stream>>>(qb, kb, amask, scb, 0, S_);
  softmax_kernel<<<(4*NH_*S_)/4, blk, 0, stream>>>(scb, S_, 4*NH_*S_);
  pv_mfma<<<dim3(4, 4*NH_), blk, 0, stream>>>((short*)scb, vT, ab, 0, S_);
  proj_o_staged<<<dim3(16, 16), blk, 0, stream>>>(ab, saot, saob, hidden, resid, D_, D_);

  // ---- cross attention (all 4 batches in one pass) ----
  ln_kernel<<<M, blk, 0, stream>>>(resid, ln2g, ln2b, xlnb);
  proj_staged<<<dim3(16, 16), blk, 0, stream>>>(xlnb, caqt, caqb, qb, 0.125f, D_, D_);
  cast_f2b<<<(B_*SK_*D_)/1024, blk, 0, stream>>>(enc, encb, B_*SK_*D_);
  proj_mfma<<<dim3(4, 32), blk, 0, stream>>>(encb, cakt, cakb, kb, 1.0f, 256, D_);
  proj_v_mfma<<<dim3(4, 32), blk, 0, stream>>>(encb, cavt, cavb, vT, 512, D_);
  qk_mfma<<<dim3(8, 4, 4*NH_), blk, 0, stream>>>(qb, kb, emask, scb, 0, SK_);
  softmax_kernel<<<(4*NH_*S_)/4, blk, 0, stream>>>(scb, SK_, 4*NH_*S_);
  pv_mfma<<<dim3(4, 4*NH_), blk, 0, stream>>>((short*)scb, vT, ab, 0, SK_);
  proj_o_staged<<<dim3(16, 16), blk, 0, stream>>>(ab, caot, caob, resid, resid, D_, D_);

  // ---- MoE (all experts parallel, LDS-staged GEMMs) ----
  ln_kernel<<<M, blk, 0, stream>>>(resid, ln3g, ln3b, xlnb);
  moe_gate_mfma<<<dim3(DE_/128, M/64, NE_), blk, 0, stream>>>(xlnb, w1t, w3t, Hs, coef, slot);
  moe_down_mfma<<<dim3(D_/128, M/64, NE_*4), blk, 0, stream>>>(Hs, w2t, resid, coef, slot);
}

// Round 12
// 722.365 us; speedup vs baseline: 1.3887x; 1.0042x over previous
//
#include <hip/hip_runtime.h>
#include <math.h>

#define B_   4
#define S_   256
#define SK_  512
#define D_   1024
#define NH_  16
#define NKV_ 4
#define HD_  64
#define DE_  4096
#define NE_  8

typedef __attribute__((ext_vector_type(8))) short bf16x8;
typedef __attribute__((ext_vector_type(4))) float f32x4;

struct __align__(8) s4 { short x, y, z, w; };

#define MFMA(a,b,c) __builtin_amdgcn_mfma_f32_16x16x32_bf16(a,b,c,0,0,0)

__device__ __forceinline__ unsigned short f2b(float f) {  // RNE
  union { float f; unsigned u; } v; v.f = f;
  unsigned r = v.u + 0x7FFF + ((v.u >> 16) & 1);
  return (unsigned short)(r >> 16);
}

__device__ __forceinline__ unsigned short f2bh(float f) {  // round-half-up (matches old weight path)
  return (unsigned short)((__float_as_uint(f) + 0x8000u) >> 16);
}

// ---------------- transpose-convert: fp32 W[K][N] -> bf16 Wt[N][K], one 64x64 tile/block ----
__device__ __forceinline__ void tconv_tile(float (*T)[65],
                                           const float* __restrict__ W,
                                           short* __restrict__ Wt,
                                           int N, int K, int n0, int k0) {
  int t = threadIdx.x;
  int kk = t >> 4, n4 = (t & 15) * 4;
#pragma unroll
  for (int it = 0; it < 4; ++it) {
    float4 v = *(const float4*)(W + (size_t)(k0 + kk + 16 * it) * N + n0 + n4);
    T[kk + 16 * it][n4 + 0] = v.x;
    T[kk + 16 * it][n4 + 1] = v.y;
    T[kk + 16 * it][n4 + 2] = v.z;
    T[kk + 16 * it][n4 + 3] = v.w;
  }
  __syncthreads();
  int n = t >> 2, kb = (t & 3) * 16;
  bf16x8 o0, o1;
#pragma unroll
  for (int j = 0; j < 8; ++j) o0[j] = (short)f2bh(T[kb + j][n]);
#pragma unroll
  for (int j = 0; j < 8; ++j) o1[j] = (short)f2bh(T[kb + 8 + j][n]);
  short* dst = Wt + (size_t)(n0 + n) * K + k0 + kb;
  *(bf16x8*)dst = o0;
  *(bf16x8*)(dst + 8) = o1;
}

struct P8 {
  const float* s[8];
  short* d[8];
  int n[8];
};

// all 8 attention weights (K = D_ = 1024 for each); z picks the matrix
__global__ __launch_bounds__(256) void tconv_attn(P8 p) {
  int z = blockIdx.z;
  int N = p.n[z];
  if ((int)blockIdx.x * 64 >= N) return;
  __shared__ float T[64][65];
  tconv_tile(T, p.s[z], p.d[z], N, D_, blockIdx.x * 64, blockIdx.y * 64);
}

// ---------------- MoE transpose, pipelined 2 rounds, TWO LDS buffers (no reuse) ------------
// Block handles 64n x 128k: round r at k0 + r*64. Loads for round 1 issue before barrier 1,
// hiding their latency under round 0's convert/store.
__device__ __forceinline__ void tconv_tile2(float (*T0)[65], float (*T1)[65],
                                            const float* __restrict__ W,
                                            short* __restrict__ Wt,
                                            int N, int K, int n0, int k0) {
  int t = threadIdx.x;
  int kk = t >> 4, n4 = (t & 15) * 4;     // load coords: row kk+16*it, cols n4..n4+3
  int n = t >> 2, kb = (t & 3) * 16;      // store coords
  const float* src = W + (size_t)(k0 + kk) * N + n0 + n4;
  float4 a0 = *(const float4*)(src);
  float4 a1 = *(const float4*)(src + (size_t)16 * N);
  float4 a2 = *(const float4*)(src + (size_t)32 * N);
  float4 a3 = *(const float4*)(src + (size_t)48 * N);
  const float* s1 = src + (size_t)64 * N;
  float4 b0 = *(const float4*)(s1);
  float4 b1 = *(const float4*)(s1 + (size_t)16 * N);
  float4 b2 = *(const float4*)(s1 + (size_t)32 * N);
  float4 b3 = *(const float4*)(s1 + (size_t)48 * N);
  T0[kk     ][n4+0]=a0.x; T0[kk     ][n4+1]=a0.y; T0[kk     ][n4+2]=a0.z; T0[kk     ][n4+3]=a0.w;
  T0[kk + 16][n4+0]=a1.x; T0[kk + 16][n4+1]=a1.y; T0[kk + 16][n4+2]=a1.z; T0[kk + 16][n4+3]=a1.w;
  T0[kk + 32][n4+0]=a2.x; T0[kk + 32][n4+1]=a2.y; T0[kk + 32][n4+2]=a2.z; T0[kk + 32][n4+3]=a2.w;
  T0[kk + 48][n4+0]=a3.x; T0[kk + 48][n4+1]=a3.y; T0[kk + 48][n4+2]=a3.z; T0[kk + 48][n4+3]=a3.w;
  __syncthreads();                        // T0 complete
  {
    bf16x8 o0, o1;
#pragma unroll
    for (int j = 0; j < 8; ++j) o0[j] = (short)f2bh(T0[kb + j][n]);
#pragma unroll
    for (int j = 0; j < 8; ++j) o1[j] = (short)f2bh(T0[kb + 8 + j][n]);
    short* dst = Wt + (size_t)(n0 + n) * K + k0 + kb;
    *(bf16x8*)dst = o0;
    *(bf16x8*)(dst + 8) = o1;
  }
  T1[kk     ][n4+0]=b0.x; T1[kk     ][n4+1]=b0.y; T1[kk     ][n4+2]=b0.z; T1[kk     ][n4+3]=b0.w;
  T1[kk + 16][n4+0]=b1.x; T1[kk + 16][n4+1]=b1.y; T1[kk + 16][n4+2]=b1.z; T1[kk + 16][n4+3]=b1.w;
  T1[kk + 32][n4+0]=b2.x; T1[kk + 32][n4+1]=b2.y; T1[kk + 32][n4+2]=b2.z; T1[kk + 32][n4+3]=b2.w;
  T1[kk + 48][n4+0]=b3.x; T1[kk + 48][n4+1]=b3.y; T1[kk + 48][n4+2]=b3.z; T1[kk + 48][n4+3]=b3.w;
  __syncthreads();                        // T1 complete
  {
    bf16x8 o0, o1;
#pragma unroll
    for (int j = 0; j < 8; ++j) o0[j] = (short)f2bh(T1[kb + j][n]);
#pragma unroll
    for (int j = 0; j < 8; ++j) o1[j] = (short)f2bh(T1[kb + 8 + j][n]);
    short* dst = Wt + (size_t)(n0 + n) * K + k0 + 64 + kb;
    *(bf16x8*)dst = o0;
    *(bf16x8*)(dst + 8) = o1;
  }
}

// ALL experts in one launch: z = e*3 + m; m=0:w1, m=1:w3 ([1024][4096] -> [4096][1024]),
// m=2: w2 ([4096][1024] -> [1024][4096]). 512 blocks (32x16) per matrix. Inactive experts exit.
__global__ __launch_bounds__(256) void tconv_moe(const float* __restrict__ w1,
                                                 const float* __restrict__ w3,
                                                 const float* __restrict__ w2,
                                                 short* __restrict__ w1t,
                                                 short* __restrict__ w3t,
                                                 short* __restrict__ w2t,
                                                 const int* __restrict__ eact) {
  int z = blockIdx.z;
  int e = z / 3, m = z - e * 3;
  if (!eact[e]) return;
  __shared__ float T0[64][65];
  __shared__ float T1[64][65];
  int lin = blockIdx.y * 32 + blockIdx.x;   // 0..511
  size_t off = (size_t)e * D_ * DE_;
  if (m == 0) {        // [1024][4096]: 64 n-tiles x 8 k-pairs
    tconv_tile2(T0, T1, w1 + off, w1t + off, DE_, D_, (lin & 63) * 64, (lin >> 6) * 128);
  } else if (m == 1) {
    tconv_tile2(T0, T1, w3 + off, w3t + off, DE_, D_, (lin & 63) * 64, (lin >> 6) * 128);
  } else {             // [4096][1024]: 16 n-tiles x 32 k-pairs
    tconv_tile2(T0, T1, w2 + off, w2t + off, D_, DE_, (lin & 15) * 64, (lin >> 4) * 128);
  }
}

// ---------------- layernorm: fp32 in, bf16 out ----------------
__global__ __launch_bounds__(256) void ln_kernel(const float* __restrict__ x,
                                                 const float* __restrict__ g,
                                                 const float* __restrict__ be,
                                                 short* __restrict__ y) {
  int row = blockIdx.x, tid = threadIdx.x;
  const float4 v = ((const float4*)(x + (size_t)row * D_))[tid];
  float s  = v.x + v.y + v.z + v.w;
  float s2 = v.x*v.x + v.y*v.y + v.z*v.z + v.w*v.w;
  __shared__ float r1[256], r2[256];
  r1[tid] = s; r2[tid] = s2; __syncthreads();
  for (int off = 128; off > 0; off >>= 1) {
    if (tid < off) { r1[tid] += r1[tid+off]; r2[tid] += r2[tid+off]; }
    __syncthreads();
  }
  float mean = r1[0] * (1.0f / D_);
  float var  = r2[0] * (1.0f / D_) - mean * mean;
  float inv  = rsqrtf(var + 1e-5f);
  int c = tid * 4;
  s4 o;
  o.x = (short)f2b((v.x - mean) * inv * g[c]   + be[c]);
  o.y = (short)f2b((v.y - mean) * inv * g[c+1] + be[c+1]);
  o.z = (short)f2b((v.z - mean) * inv * g[c+2] + be[c+2]);
  o.w = (short)f2b((v.w - mean) * inv * g[c+3] + be[c+3]);
  *(s4*)(y + (size_t)row * D_ + c) = o;
}

// ---------------- cast fp32 -> bf16 ----------------
__global__ void cast_f2b(const float* __restrict__ in, short* __restrict__ out, int n) {
  int i = (blockIdx.x * 256 + threadIdx.x) * 4;
  if (i < n) {
    float4 v = *(const float4*)(in + i);
    s4 o; o.x=(short)f2b(v.x); o.y=(short)f2b(v.y); o.z=(short)f2b(v.z); o.w=(short)f2b(v.w);
    *(s4*)(out + i) = o;
  }
}

// ---------------- projection (direct loads, kept for V): Cb = bf16((A@W+b)*s) ----
__global__ __launch_bounds__(256) void proj_mfma(const short* __restrict__ A,
                                                 const short* __restrict__ Wt,
                                                 const float* __restrict__ bias,
                                                 short* __restrict__ Cb,
                                                 float scale, int N, int K) {
  int bn = blockIdx.x * 64, bm = blockIdx.y * 64;
  int lane = threadIdx.x & 63, wv = threadIdx.x >> 6;
  int wm = (wv & 1) * 32, wn = (wv >> 1) * 32;
  int quad = lane >> 4, l16 = lane & 15;
  f32x4 z4 = {0.f,0.f,0.f,0.f};
  f32x4 acc[2][2] = {{z4,z4},{z4,z4}};
  const short* a0p = A + (size_t)(bm + wm + l16) * K;
  const short* a1p = a0p + (size_t)16 * K;
  const short* w0p = Wt + (size_t)(bn + wn + l16) * K;
  const short* w1p = w0p + (size_t)16 * K;
#pragma unroll 2
  for (int k0 = 0; k0 < K; k0 += 32) {
    int ka = k0 + quad * 8;
    bf16x8 a0 = *(const bf16x8*)(a0p + ka);
    bf16x8 a1 = *(const bf16x8*)(a1p + ka);
    bf16x8 b0 = *(const bf16x8*)(w0p + ka);
    bf16x8 b1 = *(const bf16x8*)(w1p + ka);
    acc[0][0] = MFMA(a0, b0, acc[0][0]);
    acc[0][1] = MFMA(a0, b1, acc[0][1]);
    acc[1][0] = MFMA(a1, b0, acc[1][0]);
    acc[1][1] = MFMA(a1, b1, acc[1][1]);
  }
#pragma unroll
  for (int i = 0; i < 2; ++i)
#pragma unroll
    for (int j = 0; j < 2; ++j) {
      int n = bn + wn + j*16 + l16;
      float bs = bias[n];
#pragma unroll
      for (int r = 0; r < 4; ++r) {
        int m = bm + wm + i*16 + quad*4 + r;
        Cb[(size_t)m * N + n] = (short)f2b((acc[i][j][r] + bs) * scale);
      }
    }
}

// ---------------- staged projection (LDS 2-phase, Q/K): Cb = bf16((A@W + bias)*scale) ------
__global__ __launch_bounds__(256) void proj_staged(const short* __restrict__ A,
                                                   const short* __restrict__ Wt,
                                                   const float* __restrict__ bias,
                                                   short* __restrict__ Cb,
                                                   float scale, int N, int K) {
  int bn = blockIdx.x * 64, bm = blockIdx.y * 64;
  int lane = threadIdx.x & 63, wv = threadIdx.x >> 6;
  int wm = (wv & 1) * 32, wn = (wv >> 1) * 32;
  int quad = lane >> 4, l16 = lane & 15;
  int r4 = lane >> 2, c4 = lane & 3;
  __shared__ short ldsA[2][64 * 32];
  __shared__ short ldsB[2][64 * 32];
  const short* gA = A  + (size_t)(bm + wv * 16 + r4) * K + c4 * 8;
  const short* gB = Wt + (size_t)(bn + wv * 16 + r4) * K + c4 * 8;
  f32x4 z4 = {0.f,0.f,0.f,0.f};
  f32x4 acc[2][2] = {{z4,z4},{z4,z4}};
#define PSTAGE(cc, k0)                                                                \
  do {                                                                                \
    __builtin_amdgcn_global_load_lds(gA + (k0), &ldsA[cc][wv * 512], 16, 0, 0);       \
    __builtin_amdgcn_global_load_lds(gB + (k0), &ldsB[cc][wv * 512], 16, 0, 0);       \
  } while (0)
#define PCOMP(cc)                                                                     \
  do {                                                                                \
    bf16x8 a0 = *(const bf16x8*)&ldsA[cc][(wm + l16) * 32 + quad * 8];                \
    bf16x8 a1 = *(const bf16x8*)&ldsA[cc][(wm + 16 + l16) * 32 + quad * 8];           \
    bf16x8 b0 = *(const bf16x8*)&ldsB[cc][(wn + l16) * 32 + quad * 8];                \
    bf16x8 b1 = *(const bf16x8*)&ldsB[cc][(wn + 16 + l16) * 32 + quad * 8];           \
    acc[0][0] = MFMA(a0, b0, acc[0][0]);                                              \
    acc[0][1] = MFMA(a0, b1, acc[0][1]);                                              \
    acc[1][0] = MFMA(a1, b0, acc[1][0]);                                              \
    acc[1][1] = MFMA(a1, b1, acc[1][1]);                                              \
  } while (0)
  PSTAGE(0, 0);
  __syncthreads();
  int cur = 0;
  for (int t = 0; t < K / 32 - 1; ++t) {
    PSTAGE(cur ^ 1, (t + 1) * 32);
    PCOMP(cur);
    __syncthreads();
    cur ^= 1;
  }
  PCOMP(cur);
#undef PSTAGE
#undef PCOMP
#pragma unroll
  for (int i = 0; i < 2; ++i)
#pragma unroll
    for (int j = 0; j < 2; ++j) {
      int n = bn + wn + j*16 + l16;
      float bs = bias[n];
#pragma unroll
      for (int r = 0; r < 4; ++r) {
        int m = bm + wm + i*16 + quad*4 + r;
        Cb[(size_t)m * N + n] = (short)f2b((acc[i][j][r] + bs) * scale);
      }
    }
}

// ---------------- staged O projection: out fp32 = A@W + bias + residin ----------------
__global__ __launch_bounds__(256) void proj_o_staged(const short* __restrict__ A,
                                                     const short* __restrict__ Wt,
                                                     const float* __restrict__ bias,
                                                     const float* __restrict__ rin,
                                                     float* __restrict__ C, int N, int K) {
  int bn = blockIdx.x * 64, bm = blockIdx.y * 64;
  int lane = threadIdx.x & 63, wv = threadIdx.x >> 6;
  int wm = (wv & 1) * 32, wn = (wv >> 1) * 32;
  int quad = lane >> 4, l16 = lane & 15;
  int r4 = lane >> 2, c4 = lane & 3;
  __shared__ short ldsA[2][64 * 32];
  __shared__ short ldsB[2][64 * 32];
  const short* gA = A  + (size_t)(bm + wv * 16 + r4) * K + c4 * 8;
  const short* gB = Wt + (size_t)(bn + wv * 16 + r4) * K + c4 * 8;
  f32x4 z4 = {0.f,0.f,0.f,0.f};
  f32x4 acc[2][2] = {{z4,z4},{z4,z4}};
#define PSTAGE(cc, k0)                                                                \
  do {                                                                                \
    __builtin_amdgcn_global_load_lds(gA + (k0), &ldsA[cc][wv * 512], 16, 0, 0);       \
    __builtin_amdgcn_global_load_lds(gB + (k0), &ldsB[cc][wv * 512], 16, 0, 0);       \
  } while (0)
#define PCOMP(cc)                                                                     \
  do {                                                                                \
    bf16x8 a0 = *(const bf16x8*)&ldsA[cc][(wm + l16) * 32 + quad * 8];                \
    bf16x8 a1 = *(const bf16x8*)&ldsA[cc][(wm + 16 + l16) * 32 + quad * 8];           \
    bf16x8 b0 = *(const bf16x8*)&ldsB[cc][(wn + l16) * 32 + quad * 8];                \
    bf16x8 b1 = *(const bf16x8*)&ldsB[cc][(wn + 16 + l16) * 32 + quad * 8];           \
    acc[0][0] = MFMA(a0, b0, acc[0][0]);                                              \
    acc[0][1] = MFMA(a0, b1, acc[0][1]);                                              \
    acc[1][0] = MFMA(a1, b0, acc[1][0]);                                              \
    acc[1][1] = MFMA(a1, b1, acc[1][1]);                                              \
  } while (0)
  PSTAGE(0, 0);
  __syncthreads();
  int cur = 0;
  for (int t = 0; t < K / 32 - 1; ++t) {
    PSTAGE(cur ^ 1, (t + 1) * 32);
    PCOMP(cur);
    __syncthreads();
    cur ^= 1;
  }
  PCOMP(cur);
#undef PSTAGE
#undef PCOMP
#pragma unroll
  for (int i = 0; i < 2; ++i)
#pragma unroll
    for (int j = 0; j < 2; ++j) {
      int n = bn + wn + j*16 + l16;
      float bs = bias[n];
#pragma unroll
      for (int r = 0; r < 4; ++r) {
        int m = bm + wm + i*16 + quad*4 + r;
        C[(size_t)m * N + n] = acc[i][j][r] + bs + rin[(size_t)m * N + n];
      }
    }
}

// ---------------- V projection with transposed output: vT[b][256 d][512 skv] ----------------
__global__ __launch_bounds__(256) void proj_v_mfma(const short* __restrict__ A,
                                                   const short* __restrict__ Wt,
                                                   const float* __restrict__ bias,
                                                   short* __restrict__ vT,
                                                   int SKV, int K) {
  int bn = blockIdx.x * 64, bm = blockIdx.y * 64;
  int lane = threadIdx.x & 63, wv = threadIdx.x >> 6;
  int wm = (wv & 1) * 32, wn = (wv >> 1) * 32;
  int quad = lane >> 4, l16 = lane & 15;
  f32x4 z4 = {0.f,0.f,0.f,0.f};
  f32x4 acc[2][2] = {{z4,z4},{z4,z4}};
  const short* a0p = A + (size_t)(bm + wm + l16) * K;
  const short* a1p = a0p + (size_t)16 * K;
  const short* w0p = Wt + (size_t)(bn + wn + l16) * K;
  const short* w1p = w0p + (size_t)16 * K;
#pragma unroll 2
  for (int k0 = 0; k0 < K; k0 += 32) {
    int ka = k0 + quad * 8;
    bf16x8 a0 = *(const bf16x8*)(a0p + ka);
    bf16x8 a1 = *(const bf16x8*)(a1p + ka);
    bf16x8 b0 = *(const bf16x8*)(w0p + ka);
    bf16x8 b1 = *(const bf16x8*)(w1p + ka);
    acc[0][0] = MFMA(a0, b0, acc[0][0]);
    acc[0][1] = MFMA(a0, b1, acc[0][1]);
    acc[1][0] = MFMA(a1, b0, acc[1][0]);
    acc[1][1] = MFMA(a1, b1, acc[1][1]);
  }
  __shared__ float T[64][65];
#pragma unroll
  for (int i = 0; i < 2; ++i)
#pragma unroll
    for (int j = 0; j < 2; ++j) {
      int nl = wn + j*16 + l16;
      float bs = bias[bn + nl];
#pragma unroll
      for (int r = 0; r < 4; ++r)
        T[nl][wm + i*16 + quad*4 + r] = acc[i][j][r] + bs;
    }
  __syncthreads();
  int t = threadIdx.x;
  int nl = t >> 2, m4 = (t & 3) * 16;
  int bb = bm / SKV, skv0 = bm % SKV;
  short* dst = vT + ((size_t)bb * 256 + bn + nl) * 512 + skv0 + m4;
  bf16x8 o0, o1;
#pragma unroll
  for (int ii = 0; ii < 8; ++ii) o0[ii] = (short)f2b(T[nl][m4 + ii]);
#pragma unroll
  for (int ii = 0; ii < 8; ++ii) o1[ii] = (short)f2b(T[nl][m4 + 8 + ii]);
  *(bf16x8*)dst = o0;
  *(bf16x8*)(dst + 8) = o1;
}

// ---------------- QK^T + mask -> fp32 scores ----------------
__global__ __launch_bounds__(256) void qk_mfma(const short* __restrict__ Q,
                                               const short* __restrict__ Kb,
                                               const float* __restrict__ mask,
                                               float* __restrict__ sc,
                                               int b0, int SKV) {
  int z = blockIdx.z, zb = z >> 4, h = z & 15, b = b0 + zb, kvh = h >> 2;
  int bk = blockIdx.x * 64, bq = blockIdx.y * 64;
  int lane = threadIdx.x & 63, wv = threadIdx.x >> 6;
  int wm = (wv & 1) * 32, wn = (wv >> 1) * 32;
  int quad = lane >> 4, l16 = lane & 15;
  f32x4 z4 = {0.f,0.f,0.f,0.f};
  f32x4 acc[2][2] = {{z4,z4},{z4,z4}};
  const short* q0 = Q + (size_t)(b*S_ + bq + wm + l16) * D_ + h * HD_;
  const short* q1 = q0 + (size_t)16 * D_;
  const short* k0p = Kb + (size_t)(b*SKV + bk + wn + l16) * (NKV_*HD_) + kvh * HD_;
  const short* k1p = k0p + (size_t)16 * (NKV_*HD_);
#pragma unroll
  for (int d0 = 0; d0 < HD_; d0 += 32) {
    int ka = d0 + quad * 8;
    bf16x8 a0 = *(const bf16x8*)(q0 + ka);
    bf16x8 a1 = *(const bf16x8*)(q1 + ka);
    bf16x8 b0f = *(const bf16x8*)(k0p + ka);
    bf16x8 b1f = *(const bf16x8*)(k1p + ka);
    acc[0][0] = MFMA(a0, b0f, acc[0][0]);
    acc[0][1] = MFMA(a0, b1f, acc[0][1]);
    acc[1][0] = MFMA(a1, b0f, acc[1][0]);
    acc[1][1] = MFMA(a1, b1f, acc[1][1]);
  }
#pragma unroll
  for (int i = 0; i < 2; ++i)
#pragma unroll
    for (int j = 0; j < 2; ++j) {
      int n = bk + wn + j*16 + l16;
#pragma unroll
      for (int r = 0; r < 4; ++r) {
        int m = bq + wm + i*16 + quad*4 + r;
        sc[((size_t)(zb*NH_ + h) * S_ + m) * SKV + n] =
            acc[i][j][r] + mask[((size_t)(b*S_ + m)) * SKV + n];
      }
    }
}

// ---------------- row softmax: fp32 scores in, bf16 P out (in place) ----------------
__global__ __launch_bounds__(256) void softmax_kernel(float* __restrict__ sc, int SKV, int nrows) {
  int row = blockIdx.x * 4 + (threadIdx.x >> 6);
  int lane = threadIdx.x & 63;
  if (row >= nrows) return;
  float* rp = sc + (size_t)row * SKV;
  short* sp = (short*)rp;
  float4 v[2];
  int nc = SKV >> 8;
  float mx = -1e30f;
#pragma unroll
  for (int c = 0; c < 2; ++c)
    if (c < nc) {
      v[c] = *(float4*)(rp + c*256 + lane*4);
      mx = fmaxf(mx, fmaxf(fmaxf(v[c].x, v[c].y), fmaxf(v[c].z, v[c].w)));
    }
#pragma unroll
  for (int m = 32; m > 0; m >>= 1) mx = fmaxf(mx, __shfl_xor(mx, m, 64));
  float ls = 0.f;
#pragma unroll
  for (int c = 0; c < 2; ++c)
    if (c < nc) {
      v[c].x = __expf(v[c].x - mx); v[c].y = __expf(v[c].y - mx);
      v[c].z = __expf(v[c].z - mx); v[c].w = __expf(v[c].w - mx);
      ls += v[c].x + v[c].y + v[c].z + v[c].w;
    }
#pragma unroll
  for (int m = 32; m > 0; m >>= 1) ls += __shfl_xor(ls, m, 64);
  float inv = 1.0f / ls;
#pragma unroll
  for (int c = 0; c < 2; ++c)
    if (c < nc) {
      s4 o;
      o.x = (short)f2b(v[c].x * inv); o.y = (short)f2b(v[c].y * inv);
      o.z = (short)f2b(v[c].z * inv); o.w = (short)f2b(v[c].w * inv);
      *(s4*)(sp + c*256 + lane*4) = o;
    }
}

// ---------------- P @ V -> attn out bf16 [b*S+q][h*64+d] ----------------
__global__ __launch_bounds__(256) void pv_mfma(const short* __restrict__ Pb,
                                               const short* __restrict__ vT,
                                               short* __restrict__ ob,
                                               int b0, int SKV) {
  int z = blockIdx.y, zb = z >> 4, h = z & 15, b = b0 + zb, kvh = h >> 2;
  int bq = blockIdx.x * 64;
  int lane = threadIdx.x & 63, wv = threadIdx.x >> 6;
  int wm = (wv & 1) * 32, wn = (wv >> 1) * 32;
  int quad = lane >> 4, l16 = lane & 15;
  f32x4 z4 = {0.f,0.f,0.f,0.f};
  f32x4 acc[2][2] = {{z4,z4},{z4,z4}};
  const short* p0 = Pb + ((size_t)(zb*NH_ + h) * S_ + bq + wm + l16) * (size_t)(2*SKV);
  const short* p1 = p0 + (size_t)16 * 2 * SKV;
  const short* v0 = vT + ((size_t)b * 256 + kvh*64 + wn + l16) * 512;
  const short* v1 = v0 + (size_t)16 * 512;
#pragma unroll 4
  for (int k0 = 0; k0 < SKV; k0 += 32) {
    int ka = k0 + quad * 8;
    bf16x8 a0 = *(const bf16x8*)(p0 + ka);
    bf16x8 a1 = *(const bf16x8*)(p1 + ka);
    bf16x8 b0f = *(const bf16x8*)(v0 + ka);
    bf16x8 b1f = *(const bf16x8*)(v1 + ka);
    acc[0][0] = MFMA(a0, b0f, acc[0][0]);
    acc[0][1] = MFMA(a0, b1f, acc[0][1]);
    acc[1][0] = MFMA(a1, b0f, acc[1][0]);
    acc[1][1] = MFMA(a1, b1f, acc[1][1]);
  }
#pragma unroll
  for (int i = 0; i < 2; ++i)
#pragma unroll
    for (int j = 0; j < 2; ++j) {
      int n = wn + j*16 + l16;
#pragma unroll
      for (int r = 0; r < 4; ++r) {
        int m = bq + wm + i*16 + quad*4 + r;
        ob[(size_t)(b*S_ + m) * D_ + h*HD_ + n] = (short)f2b(acc[i][j][r]);
      }
    }
}

// ---------------- MoE gate, LDS-staged 2-phase: H = bf16(gelu(x@W1e) * (x@W3e)) ----------------
__global__ __launch_bounds__(256) void moe_gate_mfma(const short* __restrict__ xlnb,
                                                     const short* __restrict__ w1t,
                                                     const short* __restrict__ w3t,
                                                     short* __restrict__ Hs,
                                                     const float* __restrict__ coef,
                                                     const int* __restrict__ slot) {
  int e = blockIdx.z;
  int bn = blockIdx.x * 128, bm = blockIdx.y * 64;
  int b = bm >> 8;
  if (coef[e * B_ + b] == 0.0f) return;     // block-uniform: safe before barriers
  int sl = slot[e * B_ + b];
  int lane = threadIdx.x & 63, wv = threadIdx.x >> 6;
  int wm = (wv & 1) * 32, wn = (wv >> 1) * 64;
  int quad = lane >> 4, l16 = lane & 15;
  int r4 = lane >> 2, c4 = lane & 3;        // staging: row-in-seg, 16B chunk

  __shared__ short ldsA[2][64 * 32];        // [row][k] 64B rows
  __shared__ short ldsB1[2][128 * 32];
  __shared__ short ldsB3[2][128 * 32];

  size_t eoff = (size_t)e * D_ * DE_;
  const short* gA  = xlnb + (size_t)(bm + wv * 16 + r4) * D_ + c4 * 8;
  const short* gB1 = w1t + eoff + (size_t)(bn + wv * 32 + r4) * D_ + c4 * 8;
  const short* gB3 = w3t + eoff + (size_t)(bn + wv * 32 + r4) * D_ + c4 * 8;

  f32x4 z4 = {0.f,0.f,0.f,0.f};
  f32x4 acc1[2][4] = {{z4,z4,z4,z4},{z4,z4,z4,z4}};
  f32x4 acc3[2][4] = {{z4,z4,z4,z4},{z4,z4,z4,z4}};

#define GATE_STAGE(cc, k0)                                                              \
  do {                                                                                  \
    __builtin_amdgcn_global_load_lds(gA + (k0),                 &ldsA[cc][wv*512], 16, 0, 0);  \
    __builtin_amdgcn_global_load_lds(gB1 + (k0),                &ldsB1[cc][wv*1024], 16, 0, 0);\
    __builtin_amdgcn_global_load_lds(gB1 + (size_t)16*D_ + (k0), &ldsB1[cc][wv*1024+512], 16, 0, 0);\
    __builtin_amdgcn_global_load_lds(gB3 + (k0),                &ldsB3[cc][wv*1024], 16, 0, 0);\
    __builtin_amdgcn_global_load_lds(gB3 + (size_t)16*D_ + (k0), &ldsB3[cc][wv*1024+512], 16, 0, 0);\
  } while (0)

#define GATE_COMP(cc)                                                                   \
  do {                                                                                  \
    bf16x8 a[2], f1[4], f3[4];                                                          \
    a[0] = *(const bf16x8*)&ldsA[cc][(wm + l16) * 32 + quad * 8];                       \
    a[1] = *(const bf16x8*)&ldsA[cc][(wm + 16 + l16) * 32 + quad * 8];                  \
    _Pragma("unroll")                                                                   \
    for (int ni = 0; ni < 4; ++ni) {                                                    \
      f1[ni] = *(const bf16x8*)&ldsB1[cc][(wn + ni*16 + l16) * 32 + quad * 8];          \
      f3[ni] = *(const bf16x8*)&ldsB3[cc][(wn + ni*16 + l16) * 32 + quad * 8];          \
    }                                                                                   \
    _Pragma("unroll")                                                                   \
    for (int mi = 0; mi < 2; ++mi)                                                      \
      _Pragma("unroll")                                                                 \
      for (int ni = 0; ni < 4; ++ni) {                                                  \
        acc1[mi][ni] = MFMA(a[mi], f1[ni], acc1[mi][ni]);                               \
        acc3[mi][ni] = MFMA(a[mi], f3[ni], acc3[mi][ni]);                               \
      }                                                                                  \
  } while (0)

  GATE_STAGE(0, 0);
  __syncthreads();
  int cur = 0;
  for (int t = 0; t < (D_ / 32) - 1; ++t) {
    GATE_STAGE(cur ^ 1, (t + 1) * 32);   // async prefetch, hides under compute
    GATE_COMP(cur);
    __syncthreads();                     // drains vmcnt -> next buffer ready
    cur ^= 1;
  }
  GATE_COMP(cur);
#undef GATE_STAGE
#undef GATE_COMP

  short* Hp = Hs + ((size_t)(sl * B_ + b) * S_ + (bm & 255)) * DE_;
#pragma unroll
  for (int mi = 0; mi < 2; ++mi)
#pragma unroll
    for (int ni = 0; ni < 4; ++ni) {
      int n = bn + wn + ni * 16 + l16;
#pragma unroll
      for (int r = 0; r < 4; ++r) {
        int lm = wm + mi * 16 + quad * 4 + r;
        float c1 = acc1[mi][ni][r], c3 = acc3[mi][ni][r];
        float g = 0.5f * c1 * (1.0f + erff(c1 * 0.70710678118654752f));
        Hp[(size_t)lm * DE_ + n] = (short)f2b(g * c3);
      }
    }
}

// ---------------- MoE down, LDS-staged 2-phase: resid += coef * (H @ W2e), 4-way K-split ----
__global__ __launch_bounds__(256) void moe_down_mfma(const short* __restrict__ Hs,
                                                     const short* __restrict__ w2t,
                                                     float* resid,
                                                     const float* __restrict__ coef,
                                                     const int* __restrict__ slot) {
  int zc = blockIdx.z;
  int e = zc >> 2, kc = zc & 3;
  int bn = blockIdx.x * 128, bm = blockIdx.y * 64;
  int b = bm >> 8;
  float cf = coef[e * B_ + b];
  if (cf == 0.0f) return;
  int sl = slot[e * B_ + b];
  int lane = threadIdx.x & 63, wv = threadIdx.x >> 6;
  int wm = (wv & 1) * 32, wn = (wv >> 1) * 64;
  int quad = lane >> 4, l16 = lane & 15;
  int r4 = lane >> 2, c4 = lane & 3;

  __shared__ short ldsA[2][64 * 32];
  __shared__ short ldsB[2][128 * 32];

  const short* gA = Hs + ((size_t)(sl * B_ + b) * S_ + (bm & 255) + wv * 16 + r4) * DE_
                    + kc * 1024 + c4 * 8;
  const short* gB = w2t + (size_t)e * DE_ * D_ + (size_t)(bn + wv * 32 + r4) * DE_
                    + kc * 1024 + c4 * 8;

  f32x4 z4 = {0.f,0.f,0.f,0.f};
  f32x4 acc[2][4] = {{z4,z4,z4,z4},{z4,z4,z4,z4}};

#define DOWN_STAGE(cc, k0)                                                              \
  do {                                                                                  \
    __builtin_amdgcn_global_load_lds(gA + (k0),                  &ldsA[cc][wv*512], 16, 0, 0); \
    __builtin_amdgcn_global_load_lds(gB + (k0),                  &ldsB[cc][wv*1024], 16, 0, 0);\
    __builtin_amdgcn_global_load_lds(gB + (size_t)16*DE_ + (k0), &ldsB[cc][wv*1024+512], 16, 0, 0);\
  } while (0)

#define DOWN_COMP(cc)                                                                   \
  do {                                                                                  \
    bf16x8 a[2], f[4];                                                                  \
    a[0] = *(const bf16x8*)&ldsA[cc][(wm + l16) * 32 + quad * 8];                       \
    a[1] = *(const bf16x8*)&ldsA[cc][(wm + 16 + l16) * 32 + quad * 8];                  \
    _Pragma("unroll")                                                                   \
    for (int ni = 0; ni < 4; ++ni)                                                      \
      f[ni] = *(const bf16x8*)&ldsB[cc][(wn + ni*16 + l16) * 32 + quad * 8];            \
    _Pragma("unroll")                                                                   \
    for (int mi = 0; mi < 2; ++mi)                                                      \
      _Pragma("unroll")                                                                 \
      for (int ni = 0; ni < 4; ++ni)                                                    \
        acc[mi][ni] = MFMA(a[mi], f[ni], acc[mi][ni]);                                  \
  } while (0)

  DOWN_STAGE(0, 0);
  __syncthreads();
  int cur = 0;
  for (int t = 0; t < 31; ++t) {
    DOWN_STAGE(cur ^ 1, (t + 1) * 32);
    DOWN_COMP(cur);
    __syncthreads();
    cur ^= 1;
  }
  DOWN_COMP(cur);
#undef DOWN_STAGE
#undef DOWN_COMP

#pragma unroll
  for (int mi = 0; mi < 2; ++mi)
#pragma unroll
    for (int ni = 0; ni < 4; ++ni) {
      int n = bn + wn + ni * 16 + l16;
#pragma unroll
      for (int r = 0; r < 4; ++r) {
        int m = bm + wm + mi * 16 + quad * 4 + r;
        atomicAdd(&resid[(size_t)m * D_ + n], cf * acc[mi][ni][r]);
      }
    }
}

// ---------------- MoE routing coefficients + slots + per-expert active flags ----------------
__global__ void coef_kernel(const int* __restrict__ langs, float* __restrict__ coef,
                            int* __restrict__ slot, int* __restrict__ eact) {
  int t = threadIdx.x;
  if (t < NE_ * B_) {
    int e = t >> 2, b = t & 3;
    int l0 = langs[b*2], l1 = langs[b*2 + 1];
    int counts = (l0 > 3) + (l1 > 3);
    float rw = (counts == 0) ? 1.0f : 1.0f / (float)counts;
    bool m = (l0 == 4 + e) || (l1 == 4 + e);
    coef[t] = m ? rw : 0.0f;
    int s = 0;
    for (int ep = 0; ep < e; ++ep) s += ((l0 == 4 + ep) || (l1 == 4 + ep)) ? 1 : 0;
    slot[t] = s;
  }
  if (t < NE_) {
    int any = 0;
    for (int b = 0; b < B_; ++b) {
      int l0 = langs[b*2], l1 = langs[b*2 + 1];
      any |= (l0 == 4 + t) || (l1 == 4 + t);
    }
    eact[t] = any;
  }
}

extern "C" void kernel_launch(void* const* d_in, const int* in_sizes, int n_in,
                              void* d_out, int out_size, void* d_ws, size_t ws_size,
                              hipStream_t stream) {
  const float* hidden = (const float*)d_in[0];
  const float* enc    = (const float*)d_in[1];
  const float* amask  = (const float*)d_in[2];
  const float* emask  = (const float*)d_in[3];
  const int*   langs  = (const int*)d_in[4];
  const float* ln1g = (const float*)d_in[5];
  const float* ln1b = (const float*)d_in[6];
  const float* saqw = (const float*)d_in[7];
  const float* saqb = (const float*)d_in[8];
  const float* sakw = (const float*)d_in[9];
  const float* sakb = (const float*)d_in[10];
  const float* savw = (const float*)d_in[11];
  const float* savb = (const float*)d_in[12];
  const float* saow = (const float*)d_in[13];
  const float* saob = (const float*)d_in[14];
  const float* ln2g = (const float*)d_in[15];
  const float* ln2b = (const float*)d_in[16];
  const float* caqw = (const float*)d_in[17];
  const float* caqb = (const float*)d_in[18];
  const float* cakw = (const float*)d_in[19];
  const float* cakb = (const float*)d_in[20];
  const float* cavw = (const float*)d_in[21];
  const float* cavb = (const float*)d_in[22];
  const float* caow = (const float*)d_in[23];
  const float* caob = (const float*)d_in[24];
  const float* ln3g = (const float*)d_in[25];
  const float* ln3b = (const float*)d_in[26];
  const float* w1   = (const float*)d_in[27];
  const float* w2   = (const float*)d_in[28];
  const float* w3   = (const float*)d_in[29];

  float* resid = (float*)d_out;     // fp32 residual stream lives in d_out

  const int M = B_ * S_;            // 1024
  float* ws = (float*)d_ws;
  short* xlnb = (short*)ws;  ws += (M * D_) / 2;          //    2 MB
  short* encb = (short*)ws;  ws += (B_ * SK_ * D_) / 2;   //    4 MB
  short* qb   = (short*)ws;  ws += (M * D_) / 2;          //    2 MB
  short* kb   = (short*)ws;  ws += (B_ * SK_ * 256) / 2;  //    1 MB
  short* vT   = (short*)ws;  ws += (B_ * 256 * 512) / 2;  //    1 MB
  short* ab   = (short*)ws;  ws += (M * D_) / 2;          //    2 MB
  float* scb  = ws;          ws += B_ * NH_ * S_ * SK_;   // 33.5 MB (scores all 4 batches / MoE-H alias)
  float* coef = ws;          ws += 32;
  int*   slot = (int*)ws;    ws += 32;
  int*   eact = (int*)ws;    ws += 32;
  // bf16 transposed weights
  short* saqt = (short*)ws;  ws += (D_ * D_) / 2;
  short* sakt = (short*)ws;  ws += (D_ * 256) / 2;
  short* savt = (short*)ws;  ws += (D_ * 256) / 2;
  short* saot = (short*)ws;  ws += (D_ * D_) / 2;
  short* caqt = (short*)ws;  ws += (D_ * D_) / 2;
  short* cakt = (short*)ws;  ws += (D_ * 256) / 2;
  short* cavt = (short*)ws;  ws += (D_ * 256) / 2;
  short* caot = (short*)ws;  ws += (D_ * D_) / 2;        // attn weights total ~10 MB
  short* w1t  = (short*)ws;  ws += (size_t)NE_ * D_ * DE_ / 2;  // 64 MB (all experts)
  short* w3t  = (short*)ws;  ws += (size_t)NE_ * D_ * DE_ / 2;  // 64 MB
  short* w2t  = (short*)ws;  ws += (size_t)NE_ * D_ * DE_ / 2;  // 64 MB  — total ~250 MB (ws is 512 MB)
  short* Hs   = (short*)scb;                              // MoE hidden [2 slots][B][S][DE] bf16 = 16 MB

  dim3 blk(256);

  // ---- weight transpose-convert (attention) ----
  P8 p;
  p.s[0] = saqw; p.d[0] = saqt; p.n[0] = D_;
  p.s[1] = sakw; p.d[1] = sakt; p.n[1] = 256;
  p.s[2] = savw; p.d[2] = savt; p.n[2] = 256;
  p.s[3] = saow; p.d[3] = saot; p.n[3] = D_;
  p.s[4] = caqw; p.d[4] = caqt; p.n[4] = D_;
  p.s[5] = cakw; p.d[5] = cakt; p.n[5] = 256;
  p.s[6] = cavw; p.d[6] = cavt; p.n[6] = 256;
  p.s[7] = caow; p.d[7] = caot; p.n[7] = D_;
  tconv_attn<<<dim3(16, 16, 8), blk, 0, stream>>>(p);
  coef_kernel<<<1, 64, 0, stream>>>(langs, coef, slot, eact);
  // MoE weight transpose for all active experts (one launch, 512 blocks/matrix, pipelined)
  tconv_moe<<<dim3(32, 16, NE_ * 3), blk, 0, stream>>>(w1, w3, w2, w1t, w3t, w2t, eact);

  // ---- self attention ----
  ln_kernel<<<M, blk, 0, stream>>>(hidden, ln1g, ln1b, xlnb);
  proj_staged<<<dim3(16, 16), blk, 0, stream>>>(xlnb, saqt, saqb, qb, 0.125f, D_, D_);
  proj_staged<<<dim3(4, 16), blk, 0, stream>>>(xlnb, sakt, sakb, kb, 1.0f, 256, D_);
  proj_v_mfma<<<dim3(4, 16), blk, 0, stream>>>(xlnb, savt, savb, vT, 256, D_);
  qk_mfma<<<dim3(4, 4, 4*NH_), blk, 0, stream>>>(qb, kb, amask, scb, 0, S_);
  softmax_kernel<<<(4*NH_*S_)/4, blk, 0, stream>>>(scb, S_, 4*NH_*S_);
  pv_mfma<<<dim3(4, 4*NH_), blk, 0, stream>>>((short*)scb, vT, ab, 0, S_);
  proj_o_staged<<<dim3(16, 16), blk, 0, stream>>>(ab, saot, saob, hidden, resid, D_, D_);

  // ---- cross attention (all 4 batches in one pass) ----
  ln_kernel<<<M, blk, 0, stream>>>(resid, ln2g, ln2b, xlnb);
  proj_staged<<<dim3(16, 16), blk, 0, stream>>>(xlnb, caqt, caqb, qb, 0.125f, D_, D_);
  cast_f2b<<<(B_*SK_*D_)/1024, blk, 0, stream>>>(enc, encb, B_*SK_*D_);
  proj_staged<<<dim3(4, 32), blk, 0, stream>>>(encb, cakt, cakb, kb, 1.0f, 256, D_);
  proj_v_mfma<<<dim3(4, 32), blk, 0, stream>>>(encb, cavt, cavb, vT, 512, D_);
  qk_mfma<<<dim3(8, 4, 4*NH_), blk, 0, stream>>>(qb, kb, emask, scb, 0, SK_);
  softmax_kernel<<<(4*NH_*S_)/4, blk, 0, stream>>>(scb, SK_, 4*NH_*S_);
  pv_mfma<<<dim3(4, 4*NH_), blk, 0, stream>>>((short*)scb, vT, ab, 0, SK_);
  proj_o_staged<<<dim3(16, 16), blk, 0, stream>>>(ab, caot, caob, resid, resid, D_, D_);

  // ---- MoE (all experts parallel, LDS-staged GEMMs) ----
  ln_kernel<<<M, blk, 0, stream>>>(resid, ln3g, ln3b, xlnb);
  moe_gate_mfma<<<dim3(DE_/128, M/64, NE_), blk, 0, stream>>>(xlnb, w1t, w3t, Hs, coef, slot);
  moe_down_mfma<<<dim3(D_/128, M/64, NE_*4), blk, 0, stream>>>(Hs, w2t, resid, coef, slot);
}